// Round 13
// baseline (229.202 us; speedup 1.0000x reference)
//
#include <hip/hip_runtime.h>
#include <math.h>

// CriticGraphPolicy, MI355X (gfx950). Round 13: DIAGNOSTIC ABLATION.
// R10(VALU)/R11(latency)/R12(bytes) all ~neutral; MfmaUtil pinned ~21% across
// four structures -> stop theorizing, ablate (common mistake #8).
// mlp_kernel<HOTW,NOLDS>: V(0,0) full (writes d_out, = R12);
//   HOTW=1: weight frag addrs folded into opaque 4KB L1-hot window
//   NOLDS=1: h1 LDS write/barrier/read removed (reg keep-alives)
// Variants keep results live via asm (no DCE), store nothing.
// Per-dispatch rocprof durs give the attribution.

#define BTOT   65536
#define XUM_OFF 655360ull

// phase0 (+fused pack)
#define PK_BLK  78
#define PH_THR  512
#define PH_ROWS 128
#define PH_BLK  (BTOT / PH_ROWS)
#define F1W 0
#define F1B 2112
#define F2W 2176
#define F2B 6272
#define F3W 6336
#define F3B 8384
#define W0_FLOATS 8416

// mlp
#define ML_THR  512
#define ML_ROWS 128
#define ML_BLK  (BTOT / ML_ROWS)
#define H1S     428

typedef float  f32x4 __attribute__((ext_vector_type(4)));
typedef __bf16 bf16x8 __attribute__((ext_vector_type(8)));
typedef unsigned short u16x8 __attribute__((ext_vector_type(8)));
typedef unsigned short u16x4 __attribute__((ext_vector_type(4)));
typedef unsigned int   u32x2 __attribute__((ext_vector_type(2)));

__device__ __forceinline__ unsigned short f2b(float f) {
  union { float f; unsigned int u; } v; v.f = f;
  return (unsigned short)((v.u + 0x7fffu + ((v.u >> 16) & 1u)) >> 16);
}
__device__ __forceinline__ float b2f(unsigned short u) {
  union { unsigned int u; float f; } v; v.u = ((unsigned int)u) << 16;
  return v.f;
}
__device__ __forceinline__ f32x4 MFMA(bf16x8 a, bf16x8 b, f32x4 c) {
  return __builtin_amdgcn_mfma_f32_16x16x32_bf16(a, b, c, 0, 0, 0);
}
__device__ __forceinline__ bf16x8 ld8(const unsigned short* p) {
  return __builtin_bit_cast(bf16x8, *(const u16x8*)p);
}
__device__ __forceinline__ float ftanh(float x) {
  float e = __builtin_amdgcn_exp2f(x * 2.885390081777927f);
  return (e - 1.0f) * __builtin_amdgcn_rcpf(e + 1.0f);
}
// fragment byte offset; HOT: fold into 4KB window with opaque offset (no CSE)
template<int HOT>
__device__ __forceinline__ const unsigned short* wadr(const char* base, int idx) {
  unsigned off;
  if (HOT) { off = (unsigned)(idx & 3) * 1024u; asm volatile("" : "+v"(off)); }
  else     { off = (unsigned)idx * 1024u; }
  return (const unsigned short*)(base + off);
}

// ---------------- phase0 kernel (+fused fragment pack) -- unchanged R12 -----
struct P0 {
  const float* state; const float* action;
  const float* f1w; const float* f1b;
  const float* f2w; const float* f2b;
  const float* f3w; const float* f3b;
  const float* q1w1; const float* q1b1; const float* q1w2;
  const float* q2w1; const float* q2b1; const float* q2w2;
  unsigned short* ws;
  unsigned short* xum;
};

__global__ __launch_bounds__(PH_THR, 4) void phase0_kernel(P0 P) {
  __shared__ float w0[W0_FLOATS];
  __shared__ unsigned short hx[PH_ROWS * 68];
  const int tid = threadIdx.x;

  if (blockIdx.x < PK_BLK) {
    const int gid = blockIdx.x * PH_THR + tid;
    const int lane = gid & 63, f = gid >> 6;
    const int q = f / 312, fl = f - q * 312;
    const float* w1 = q ? P.q2w1 : P.q1w1;
    const float* b1 = q ? P.q2b1 : P.q1b1;
    const float* w2 = q ? P.q2w2 : P.q1w2;
    int nt, ks; const bool isw1 = (fl < 52);
    if (isw1) { nt = fl >> 1; ks = fl & 1; }
    else      { int fl2 = fl - 52; nt = fl2 / 13; ks = fl2 - nt * 13; }
    const int col = nt * 16 + (lane & 15);
    const int k0  = ks * 32 + (lane >> 4) * 8;
    unsigned short v[8];
    #pragma unroll
    for (int j = 0; j < 8; ++j) {
      const int k = k0 + j;
      float x = 0.f;
      if (isw1) {
        if (col < 400) {
          if (k < 39) x = w1[(6 + k) * 400 + col];
          else if (k == 39) x = b1[col];
        }
      } else {
        if (k < 400 && col < 300) x = w2[k * 300 + col];
      }
      v[j] = f2b(x);
    }
    *(u16x8*)(P.ws + (size_t)f * 512 + lane * 8) = *(const u16x8*)v;
    return;
  }

  const int row = tid >> 2, sub = tid & 3, j0 = sub * 16;
  const long grow = (long)(blockIdx.x - PK_BLK) * PH_ROWS + row;

  for (int i = tid; i < 528;  i += PH_THR) *(f32x4*)(w0 + F1W + 4*i) = *(const f32x4*)(P.f1w + 4*i);
  for (int i = tid; i < 16;   i += PH_THR) *(f32x4*)(w0 + F1B + 4*i) = *(const f32x4*)(P.f1b + 4*i);
  for (int i = tid; i < 1024; i += PH_THR) *(f32x4*)(w0 + F2W + 4*i) = *(const f32x4*)(P.f2w + 4*i);
  for (int i = tid; i < 16;   i += PH_THR) *(f32x4*)(w0 + F2B + 4*i) = *(const f32x4*)(P.f2b + 4*i);
  for (int i = tid; i < 512;  i += PH_THR) *(f32x4*)(w0 + F3W + 4*i) = *(const f32x4*)(P.f3w + 4*i);
  for (int i = tid; i < 8;    i += PH_THR) *(f32x4*)(w0 + F3B + 4*i) = *(const f32x4*)(P.f3b + 4*i);

  float sa[33];
  {
    const float4* sp = (const float4*)(P.state + grow * 32);
    #pragma unroll
    for (int c = 0; c < 8; ++c) {
      float4 v = sp[c];
      sa[c*4+0] = v.x; sa[c*4+1] = v.y; sa[c*4+2] = v.z; sa[c*4+3] = v.w;
    }
    sa[32] = P.action[grow];
  }
  __syncthreads();

  float acc[16];
  #pragma unroll
  for (int j = 0; j < 16; ++j) acc[j] = w0[F1B + j0 + j];
  #pragma unroll 4
  for (int i = 0; i < 33; ++i) {
    const float s = sa[i];
    const f32x4* wr = (const f32x4*)&w0[F1W + i * 64 + j0];
    #pragma unroll
    for (int c = 0; c < 4; ++c) {
      f32x4 wv = wr[c];
      acc[c*4+0] += s * wv[0]; acc[c*4+1] += s * wv[1];
      acc[c*4+2] += s * wv[2]; acc[c*4+3] += s * wv[3];
    }
  }
  {
    float ss = 0.f;
    #pragma unroll
    for (int j = 0; j < 16; ++j) ss += acc[j] * acc[j];
    ss += __shfl_xor(ss, 1, 64); ss += __shfl_xor(ss, 2, 64);
    const float sc = 1.f / fmaxf(sqrtf(ss), 1e-12f);
    #pragma unroll
    for (int j = 0; j < 16; ++j) hx[row * 68 + j0 + j] = f2b(ftanh(acc[j] * sc));
  }
  __syncthreads();
  #pragma unroll
  for (int j = 0; j < 16; ++j) acc[j] = w0[F2B + j0 + j];
  #pragma unroll 4
  for (int i0 = 0; i0 < 16; ++i0) {
    const u16x4 hv4 = *(const u16x4*)&hx[row * 68 + i0 * 4];
    #pragma unroll
    for (int u = 0; u < 4; ++u) {
      const float hv = b2f(hv4[u]);
      const f32x4* wr = (const f32x4*)&w0[F2W + (i0 * 4 + u) * 64 + j0];
      #pragma unroll
      for (int c = 0; c < 4; ++c) {
        f32x4 wv = wr[c];
        acc[c*4+0] += hv * wv[0]; acc[c*4+1] += hv * wv[1];
        acc[c*4+2] += hv * wv[2]; acc[c*4+3] += hv * wv[3];
      }
    }
  }
  __syncthreads();
  #pragma unroll
  for (int j = 0; j < 16; ++j) hx[row * 68 + j0 + j] = f2b(ftanh(acc[j]));
  __syncthreads();
  const int j0m = sub * 8;
  float am[8];
  #pragma unroll
  for (int j = 0; j < 8; ++j) am[j] = w0[F3B + j0m + j];
  #pragma unroll 4
  for (int i0 = 0; i0 < 16; ++i0) {
    const u16x4 hv4 = *(const u16x4*)&hx[row * 68 + i0 * 4];
    #pragma unroll
    for (int u = 0; u < 4; ++u) {
      const float hv = b2f(hv4[u]);
      const f32x4* wr = (const f32x4*)&w0[F3W + (i0 * 4 + u) * 32 + j0m];
      #pragma unroll
      for (int c = 0; c < 2; ++c) {
        f32x4 wv = wr[c];
        am[c*4+0] += hv * wv[0]; am[c*4+1] += hv * wv[1];
        am[c*4+2] += hv * wv[2]; am[c*4+3] += hv * wv[3];
      }
    }
  }
  float sm = 0.f;
  #pragma unroll
  for (int j = 0; j < 8; ++j) sm += am[j] * am[j];
  sm += __shfl_xor(sm, 1, 64); sm += __shfl_xor(sm, 2, 64);
  const float scm = 1.f / fmaxf(sqrtf(sm), 1e-12f);
  __syncthreads();
  #pragma unroll
  for (int j = 0; j < 8; ++j) hx[row * 68 + j0m + j] = f2b(am[j] * scm);
  __syncthreads();
  {
    u16x8 v0, v1;
    #pragma unroll
    for (int t = 0; t < 16; ++t) {
      const int c = j0 + t;
      unsigned short u;
      if      (c < 3)  u = f2b(sa[c]);
      else if (c < 6)  u = f2b(sa[c - 3]);
      else if (c < 38) u = hx[row * 68 + (c - 6)];
      else if (c == 38) u = f2b(sa[32]);
      else if (c == 39) u = 0x3f80;
      else              u = 0;
      if (t < 8) v0[t] = u; else v1[t - 8] = u;
    }
    unsigned short* dst = P.xum + (size_t)grow * 64 + j0;
    *(u16x8*)dst = v0;
    *(u16x8*)(dst + 8) = v1;
  }
}

// ---------------- mlp kernel (templated ablation) ----------------
struct P1 {
  const unsigned short* img; const unsigned short* xum;
  const float* q1b2; const float* q1w3; const float* q1b3;
  const float* q2b2; const float* q2w3; const float* q2b3;
  float* out;
};

template<int HOTW, int NOLDS>
__global__ __launch_bounds__(ML_THR, 2) void mlp_kernel(P1 P) {
  __shared__ __align__(16) unsigned short h1[ML_ROWS * H1S];
  __shared__ float xred[ML_ROWS * 4];

  const int tid  = threadIdx.x;
  const int lane = tid & 63, w = tid >> 6;        // 8 waves
  const int rl = lane & 15, g = lane >> 4;

  const int rp = w & 3, ch = w >> 2;              // layer1 mapping
  const int wm = w >> 2, wn = w & 3;              // layer2 mapping

  const unsigned short* xr0 = P.xum + ((size_t)blockIdx.x * ML_ROWS + rp * 32 + rl) * 64;
  const bf16x8 af0k0 = ld8(xr0 + g * 8);
  const bf16x8 af0k1 = ld8(xr0 + 32 + g * 8);
  const unsigned short* xr1 = xr0 + 16 * 64;
  const bf16x8 af1k0 = ld8(xr1 + g * 8);
  const bf16x8 af1k1 = ld8(xr1 + 32 + g * 8);

  for (int q = 0; q < 2; ++q) {
    // ---- layer1 ----
    {
      const char* w1fb = (const char*)(P.img + ((size_t)(q * 312 + ch * 26)) * 512 + lane * 8);
      unsigned short* h1w0 = &h1[(size_t)(rp * 32 + rl) * H1S + ch * 208 + g * 4];
      unsigned short* h1w1 = &h1[(size_t)(rp * 32 + 16 + rl) * H1S + ch * 208 + g * 4];
      bf16x8 wA0 = ld8(wadr<HOTW>(w1fb, 0)), wA1 = ld8(wadr<HOTW>(w1fb, 1));
      bf16x8 wB0 = ld8(wadr<HOTW>(w1fb, 2)), wB1 = ld8(wadr<HOTW>(w1fb, 3));
      for (int t = 0; t < 13; t += 2) {
        {
          f32x4 a = (f32x4){0.f, 0.f, 0.f, 0.f};
          f32x4 b = (f32x4){0.f, 0.f, 0.f, 0.f};
          a = MFMA(wA0, af0k0, a); a = MFMA(wA1, af0k1, a);
          b = MFMA(wA0, af1k0, b); b = MFMA(wA1, af1k1, b);
          if (t + 2 < 13) {
            wA0 = ld8(wadr<HOTW>(w1fb, (t + 2) * 2));
            wA1 = ld8(wadr<HOTW>(w1fb, (t + 2) * 2 + 1));
          }
          unsigned int p01, p23, q01, q23;
          const float a0 = fmaxf(a[0], 0.f), a1 = fmaxf(a[1], 0.f);
          const float a2 = fmaxf(a[2], 0.f), a3 = fmaxf(a[3], 0.f);
          const float b0 = fmaxf(b[0], 0.f), b1 = fmaxf(b[1], 0.f);
          const float b2 = fmaxf(b[2], 0.f), b3 = fmaxf(b[3], 0.f);
          asm("v_cvt_pk_bf16_f32 %0, %1, %2" : "=v"(p01) : "v"(a0), "v"(a1));
          asm("v_cvt_pk_bf16_f32 %0, %1, %2" : "=v"(p23) : "v"(a2), "v"(a3));
          asm("v_cvt_pk_bf16_f32 %0, %1, %2" : "=v"(q01) : "v"(b0), "v"(b1));
          asm("v_cvt_pk_bf16_f32 %0, %1, %2" : "=v"(q23) : "v"(b2), "v"(b3));
          if constexpr (NOLDS) {
            asm volatile("" :: "v"(p01), "v"(p23), "v"(q01), "v"(q23));
          } else {
            u32x2 pk; pk[0] = p01; pk[1] = p23;
            u32x2 qk; qk[0] = q01; qk[1] = q23;
            *(u32x2*)(h1w0 + t * 16) = pk;
            *(u32x2*)(h1w1 + t * 16) = qk;
          }
        }
        if (t + 1 < 13) {
          f32x4 a = (f32x4){0.f, 0.f, 0.f, 0.f};
          f32x4 b = (f32x4){0.f, 0.f, 0.f, 0.f};
          a = MFMA(wB0, af0k0, a); a = MFMA(wB1, af0k1, a);
          b = MFMA(wB0, af1k0, b); b = MFMA(wB1, af1k1, b);
          if (t + 3 < 13) {
            wB0 = ld8(wadr<HOTW>(w1fb, (t + 3) * 2));
            wB1 = ld8(wadr<HOTW>(w1fb, (t + 3) * 2 + 1));
          }
          unsigned int p01, p23, q01, q23;
          const float a0 = fmaxf(a[0], 0.f), a1 = fmaxf(a[1], 0.f);
          const float a2 = fmaxf(a[2], 0.f), a3 = fmaxf(a[3], 0.f);
          const float b0 = fmaxf(b[0], 0.f), b1 = fmaxf(b[1], 0.f);
          const float b2 = fmaxf(b[2], 0.f), b3 = fmaxf(b[3], 0.f);
          asm("v_cvt_pk_bf16_f32 %0, %1, %2" : "=v"(p01) : "v"(a0), "v"(a1));
          asm("v_cvt_pk_bf16_f32 %0, %1, %2" : "=v"(p23) : "v"(a2), "v"(a3));
          asm("v_cvt_pk_bf16_f32 %0, %1, %2" : "=v"(q01) : "v"(b0), "v"(b1));
          asm("v_cvt_pk_bf16_f32 %0, %1, %2" : "=v"(q23) : "v"(b2), "v"(b3));
          if constexpr (NOLDS) {
            asm volatile("" :: "v"(p01), "v"(p23), "v"(q01), "v"(q23));
          } else {
            u32x2 pk; pk[0] = p01; pk[1] = p23;
            u32x2 qk; qk[0] = q01; qk[1] = q23;
            *(u32x2*)(h1w0 + (t + 1) * 16) = pk;
            *(u32x2*)(h1w1 + (t + 1) * 16) = qk;
          }
        }
      }
    }
    if constexpr (!NOLDS) __syncthreads();        // h1 complete

    // ---- layer2 ----
    f32x4 acc2[4][5];
    #pragma unroll
    for (int mt = 0; mt < 4; ++mt)
      #pragma unroll
      for (int jn = 0; jn < 5; ++jn) acc2[mt][jn] = (f32x4){0.f, 0.f, 0.f, 0.f};
    {
      const char* w2fb = (const char*)(P.img + ((size_t)(q * 312 + 52 + wn * 65)) * 512 + lane * 8);
      bf16x8 bA[5], bB[5];
      #pragma unroll
      for (int jn = 0; jn < 5; ++jn) bA[jn] = ld8(wadr<HOTW>(w2fb, jn * 13 + 0));
      #pragma unroll
      for (int jn = 0; jn < 5; ++jn) bB[jn] = ld8(wadr<HOTW>(w2fb, jn * 13 + 1));
      for (int ks = 0; ks < 13; ks += 2) {
        {
          bf16x8 am[4];
          #pragma unroll
          for (int mt = 0; mt < 4; ++mt) {
            if constexpr (NOLDS) am[mt] = (mt & 1) ? af0k1 : af0k0;
            else am[mt] = ld8(&h1[(size_t)(wm * 64 + mt * 16 + rl) * H1S + ks * 32 + g * 8]);
          }
          #pragma unroll
          for (int jn = 0; jn < 5; ++jn)
            #pragma unroll
            for (int mt = 0; mt < 4; ++mt)
              acc2[mt][jn] = MFMA(am[mt], bA[jn], acc2[mt][jn]);
          if (ks + 2 < 13) {
            #pragma unroll
            for (int jn = 0; jn < 5; ++jn)
              bA[jn] = ld8(wadr<HOTW>(w2fb, jn * 13 + ks + 2));
          }
        }
        if (ks + 1 < 13) {
          bf16x8 am[4];
          #pragma unroll
          for (int mt = 0; mt < 4; ++mt) {
            if constexpr (NOLDS) am[mt] = (mt & 1) ? af1k1 : af1k0;
            else am[mt] = ld8(&h1[(size_t)(wm * 64 + mt * 16 + rl) * H1S + (ks + 1) * 32 + g * 8]);
          }
          #pragma unroll
          for (int jn = 0; jn < 5; ++jn)
            #pragma unroll
            for (int mt = 0; mt < 4; ++mt)
              acc2[mt][jn] = MFMA(am[mt], bB[jn], acc2[mt][jn]);
          if (ks + 3 < 13) {
            #pragma unroll
            for (int jn = 0; jn < 5; ++jn)
              bB[jn] = ld8(wadr<HOTW>(w2fb, jn * 13 + ks + 3));
          }
        }
      }
    }

    // ---- epilogue (identical in all variants; only final store differs) ----
    const float* b2p = q ? P.q2b2 : P.q1b2;
    const float* w3  = q ? P.q2w3 : P.q1w3;
    const float* b3  = q ? P.q2b3 : P.q1b3;
    float xp[4][4];
    #pragma unroll
    for (int mt = 0; mt < 4; ++mt)
      #pragma unroll
      for (int i = 0; i < 4; ++i) xp[mt][i] = 0.f;
    #pragma unroll
    for (int jn = 0; jn < 5; ++jn) {
      const int n = wn * 80 + jn * 16 + rl;
      if (n < 300) {
        const float bv = b2p[n], wv = w3[n];
        #pragma unroll
        for (int mt = 0; mt < 4; ++mt)
          #pragma unroll
          for (int i = 0; i < 4; ++i)
            xp[mt][i] += fmaxf(acc2[mt][jn][i] + bv, 0.f) * wv;
      }
    }
    #pragma unroll
    for (int off = 1; off < 16; off <<= 1)
      #pragma unroll
      for (int mt = 0; mt < 4; ++mt)
        #pragma unroll
        for (int i = 0; i < 4; ++i)
          xp[mt][i] += __shfl_xor(xp[mt][i], off, 64);
    if (rl == 0) {
      #pragma unroll
      for (int mt = 0; mt < 4; ++mt)
        #pragma unroll
        for (int i = 0; i < 4; ++i)
          xred[(wm * 64 + mt * 16 + g * 4 + i) * 4 + wn] = xp[mt][i];
    }
    __syncthreads();
    if (tid < ML_ROWS) {
      const float4 xv = *(const float4*)&xred[tid * 4];
      const float r = xv.x + xv.y + xv.z + xv.w + b3[0];
      if constexpr (HOTW == 0 && NOLDS == 0) {
        P.out[(size_t)q * BTOT + (size_t)blockIdx.x * ML_ROWS + tid] = r;
      } else {
        asm volatile("" :: "v"(r));               // keep chain live, no store
      }
    }
    __syncthreads();
  }
  // anchor h1 so LDS footprint (occupancy) is identical across variants
  if (tid == 0) ((volatile unsigned short*)h1)[0] = 0;
}

extern "C" void kernel_launch(void* const* d_in, const int* in_sizes, int n_in,
                              void* d_out, int out_size, void* d_ws, size_t ws_size,
                              hipStream_t stream) {
  (void)in_sizes; (void)n_in; (void)out_size; (void)ws_size;
  P0 A;
  A.state  = (const float*)d_in[0];
  A.action = (const float*)d_in[1];
  A.f1w = (const float*)d_in[2]; A.f1b = (const float*)d_in[3];
  A.f2w = (const float*)d_in[4]; A.f2b = (const float*)d_in[5];
  A.f3w = (const float*)d_in[6]; A.f3b = (const float*)d_in[7];
  A.q1w1 = (const float*)d_in[10]; A.q1b1 = (const float*)d_in[11]; A.q1w2 = (const float*)d_in[12];
  A.q2w1 = (const float*)d_in[16]; A.q2b1 = (const float*)d_in[17]; A.q2w2 = (const float*)d_in[18];
  A.ws  = (unsigned short*)d_ws;
  A.xum = (unsigned short*)((unsigned char*)d_ws + XUM_OFF);
  phase0_kernel<<<dim3(PK_BLK + PH_BLK), dim3(PH_THR), 0, stream>>>(A);

  P1 B;
  B.img  = (const unsigned short*)d_ws;
  B.xum  = (const unsigned short*)((unsigned char*)d_ws + XUM_OFF);
  B.q1b2 = (const float*)d_in[13]; B.q1w3 = (const float*)d_in[14]; B.q1b3 = (const float*)d_in[15];
  B.q2b2 = (const float*)d_in[19]; B.q2w3 = (const float*)d_in[20]; B.q2b3 = (const float*)d_in[21];
  B.out  = (float*)d_out;
  mlp_kernel<0, 0><<<dim3(ML_BLK), dim3(ML_THR), 0, stream>>>(B);  // real
  mlp_kernel<1, 0><<<dim3(ML_BLK), dim3(ML_THR), 0, stream>>>(B);  // hot weights
  mlp_kernel<0, 1><<<dim3(ML_BLK), dim3(ML_THR), 0, stream>>>(B);  // no LDS h1
  mlp_kernel<1, 1><<<dim3(ML_BLK), dim3(ML_THR), 0, stream>>>(B);  // pure floor
}

// Round 14
// 129.202 us; speedup vs baseline: 1.7740x; 1.7740x over previous
//
#include <hip/hip_runtime.h>
#include <math.h>

// CriticGraphPolicy, MI355X (gfx950). Round 14.
// R13 ablation: time invariant to weight path (HOTW), LDS h1 (NOLDS), HBM
// (PURE: FETCH=0, 79us) -> stall is exposed latency at 8 waves/CU with
// barrier-lockstepped waves; R9(4w/SIMD)=R12(2w/SIMD) shows intra-block waves
// don't overlap phases. Fix: CO-RESIDENT BLOCKS. K split 224/192 -> h1
// [128][228]=58.4KB; phase0 fused in (xum in LDS, aliased); total LDS 77.8KB
// -> 2 blocks/CU, 16 waves/CU, ONE dispatch round, cross-block phase overlap.

#define BTOT   65536
#define NTHR   512
#define TBROWS 128
#define NBLK   (BTOT / TBROWS)   // 512

// LDS map (bytes), SMEM = 77,824 -> 2 blocks/CU
#define O_HX   33664             // u16 [128][68] = 17,408 (after w0 f32[8416])
#define O_XRED 58368             // f32 [128][4]  =  2,048
#define O_XUM  60416             // u16 [128][68] = 17,408
#define SMEM_SZ 77824
#define H1S    228               // h1 u16 stride: 456B row = 114 dw, gcd 2 -> 2-way

// w0 float indices
#define F1W 0
#define F1B 2112
#define F2W 2176
#define F2B 6272
#define F3W 6336
#define F3B 8384

typedef float  f32x4 __attribute__((ext_vector_type(4)));
typedef __bf16 bf16x8 __attribute__((ext_vector_type(8)));
typedef unsigned short u16x8 __attribute__((ext_vector_type(8)));
typedef unsigned short u16x4 __attribute__((ext_vector_type(4)));
typedef unsigned int   u32x2 __attribute__((ext_vector_type(2)));

__device__ __forceinline__ unsigned short f2b(float f) {
  union { float f; unsigned int u; } v; v.f = f;
  return (unsigned short)((v.u + 0x7fffu + ((v.u >> 16) & 1u)) >> 16);
}
__device__ __forceinline__ float b2f(unsigned short u) {
  union { unsigned int u; float f; } v; v.u = ((unsigned int)u) << 16;
  return v.f;
}
__device__ __forceinline__ f32x4 MFMA(bf16x8 a, bf16x8 b, f32x4 c) {
  return __builtin_amdgcn_mfma_f32_16x16x32_bf16(a, b, c, 0, 0, 0);
}
__device__ __forceinline__ bf16x8 ld8(const unsigned short* p) {
  return __builtin_bit_cast(bf16x8, *(const u16x8*)p);
}
__device__ __forceinline__ float ftanh(float x) {
  float e = __builtin_amdgcn_exp2f(x * 2.885390081777927f);
  return (e - 1.0f) * __builtin_amdgcn_rcpf(e + 1.0f);
}

// ---------------- pack kernel: fragment-ordered bf16 weight images ----------
// 624 frags x 1024 B. Per q (312): w1eff [nt 26][ks 2] (52) then w2 [nt 20][ks 13].
// frag elem[lane][j] = W[k0+j][col], col = nt*16+(lane&15), k0 = ks*32+(lane>>4)*8.
struct PackP {
  const float* q1w1; const float* q1b1; const float* q1w2;
  const float* q2w1; const float* q2b1; const float* q2w2;
  unsigned short* ws;
};

__global__ void pack_weights(PackP P) {
  const int gid = blockIdx.x * 512 + threadIdx.x;   // 78*512 = 39,936 = 624*64
  const int lane = gid & 63, f = gid >> 6;
  const int q = f / 312, fl = f - q * 312;
  const float* w1 = q ? P.q2w1 : P.q1w1;
  const float* b1 = q ? P.q2b1 : P.q1b1;
  const float* w2 = q ? P.q2w2 : P.q1w2;
  int nt, ks; const bool isw1 = (fl < 52);
  if (isw1) { nt = fl >> 1; ks = fl & 1; }
  else      { int fl2 = fl - 52; nt = fl2 / 13; ks = fl2 - nt * 13; }
  const int col = nt * 16 + (lane & 15);
  const int k0  = ks * 32 + (lane >> 4) * 8;
  unsigned short v[8];
  #pragma unroll
  for (int j = 0; j < 8; ++j) {
    const int k = k0 + j;
    float x = 0.f;
    if (isw1) {
      if (col < 400) {
        if (k < 39) x = w1[(6 + k) * 400 + col];
        else if (k == 39) x = b1[col];
      }
    } else {
      if (k < 400 && col < 300) x = w2[k * 300 + col];
    }
    v[j] = f2b(x);
  }
  *(u16x8*)(P.ws + (size_t)f * 512 + lane * 8) = *(const u16x8*)v;
}

// ---------------- fused kernel: phase0 + both q-net MLPs ----------------
struct FP {
  const float* state; const float* action;
  const float* f1w; const float* f1b;
  const float* f2w; const float* f2b;
  const float* f3w; const float* f3b;
  const unsigned short* img;
  const float* q1b2; const float* q1w3; const float* q1b3;
  const float* q2b2; const float* q2w3; const float* q2b3;
  float* out;
};

__global__ __launch_bounds__(NTHR, 2) void critic_fused(FP P) {
  __shared__ __align__(16) unsigned char smem[SMEM_SZ];
  float*          w0   = (float*)smem;                       // phase0 only
  unsigned short* hx   = (unsigned short*)(smem + O_HX);     // phase0 only
  unsigned short* h1   = (unsigned short*)smem;              // k-loop (aliases w0/hx)
  float*          xred = (float*)(smem + O_XRED);
  unsigned short* xumL = (unsigned short*)(smem + O_XUM);

  const int tid  = threadIdx.x;
  const int lane = tid & 63, w = tid >> 6;        // 8 waves
  const int rl = lane & 15, g = lane >> 4;
  const int row = tid >> 2, sub = tid & 3, j0 = sub * 16;
  const long grow = (long)blockIdx.x * TBROWS + row;

  // ---------------- phase 0 (f32 VALU, weights staged to LDS) ----------------
  for (int i = tid; i < 528;  i += NTHR) *(f32x4*)(w0 + F1W + 4*i) = *(const f32x4*)(P.f1w + 4*i);
  for (int i = tid; i < 16;   i += NTHR) *(f32x4*)(w0 + F1B + 4*i) = *(const f32x4*)(P.f1b + 4*i);
  for (int i = tid; i < 1024; i += NTHR) *(f32x4*)(w0 + F2W + 4*i) = *(const f32x4*)(P.f2w + 4*i);
  for (int i = tid; i < 16;   i += NTHR) *(f32x4*)(w0 + F2B + 4*i) = *(const f32x4*)(P.f2b + 4*i);
  for (int i = tid; i < 512;  i += NTHR) *(f32x4*)(w0 + F3W + 4*i) = *(const f32x4*)(P.f3w + 4*i);
  for (int i = tid; i < 8;    i += NTHR) *(f32x4*)(w0 + F3B + 4*i) = *(const f32x4*)(P.f3b + 4*i);

  float sa[33];
  {
    const float4* sp = (const float4*)(P.state + grow * 32);
    #pragma unroll
    for (int c = 0; c < 8; ++c) {
      float4 v = sp[c];
      sa[c*4+0] = v.x; sa[c*4+1] = v.y; sa[c*4+2] = v.z; sa[c*4+3] = v.w;
    }
    sa[32] = P.action[grow];
  }
  __syncthreads();

  float acc[16];
  // fc1: h = tanh(l2norm(sa @ w1 + b1))
  #pragma unroll
  for (int j = 0; j < 16; ++j) acc[j] = w0[F1B + j0 + j];
  #pragma unroll 4
  for (int i = 0; i < 33; ++i) {
    const float s = sa[i];
    const f32x4* wr = (const f32x4*)&w0[F1W + i * 64 + j0];
    #pragma unroll
    for (int c = 0; c < 4; ++c) {
      f32x4 wv = wr[c];
      acc[c*4+0] += s * wv[0]; acc[c*4+1] += s * wv[1];
      acc[c*4+2] += s * wv[2]; acc[c*4+3] += s * wv[3];
    }
  }
  {
    float ss = 0.f;
    #pragma unroll
    for (int j = 0; j < 16; ++j) ss += acc[j] * acc[j];
    ss += __shfl_xor(ss, 1, 64); ss += __shfl_xor(ss, 2, 64);
    const float sc = 1.f / fmaxf(sqrtf(ss), 1e-12f);
    #pragma unroll
    for (int j = 0; j < 16; ++j) hx[row * 68 + j0 + j] = f2b(ftanh(acc[j] * sc));
  }
  __syncthreads();
  // fc2: h2 = tanh(h @ w2[0:64] + b2)
  #pragma unroll
  for (int j = 0; j < 16; ++j) acc[j] = w0[F2B + j0 + j];
  #pragma unroll 4
  for (int i0 = 0; i0 < 16; ++i0) {
    const u16x4 hv4 = *(const u16x4*)&hx[row * 68 + i0 * 4];
    #pragma unroll
    for (int u = 0; u < 4; ++u) {
      const float hv = b2f(hv4[u]);
      const f32x4* wr = (const f32x4*)&w0[F2W + (i0 * 4 + u) * 64 + j0];
      #pragma unroll
      for (int c = 0; c < 4; ++c) {
        f32x4 wv = wr[c];
        acc[c*4+0] += hv * wv[0]; acc[c*4+1] += hv * wv[1];
        acc[c*4+2] += hv * wv[2]; acc[c*4+3] += hv * wv[3];
      }
    }
  }
  __syncthreads();
  #pragma unroll
  for (int j = 0; j < 16; ++j) hx[row * 68 + j0 + j] = f2b(ftanh(acc[j]));
  __syncthreads();
  // fc3: msg = l2norm(h2 @ w3 + b3)
  const int j0m = sub * 8;
  float am8[8];
  #pragma unroll
  for (int j = 0; j < 8; ++j) am8[j] = w0[F3B + j0m + j];
  #pragma unroll 4
  for (int i0 = 0; i0 < 16; ++i0) {
    const u16x4 hv4 = *(const u16x4*)&hx[row * 68 + i0 * 4];
    #pragma unroll
    for (int u = 0; u < 4; ++u) {
      const float hv = b2f(hv4[u]);
      const f32x4* wr = (const f32x4*)&w0[F3W + (i0 * 4 + u) * 32 + j0m];
      #pragma unroll
      for (int c = 0; c < 2; ++c) {
        f32x4 wv = wr[c];
        am8[c*4+0] += hv * wv[0]; am8[c*4+1] += hv * wv[1];
        am8[c*4+2] += hv * wv[2]; am8[c*4+3] += hv * wv[3];
      }
    }
  }
  float sm = 0.f;
  #pragma unroll
  for (int j = 0; j < 8; ++j) sm += am8[j] * am8[j];
  sm += __shfl_xor(sm, 1, 64); sm += __shfl_xor(sm, 2, 64);
  const float scm = 1.f / fmaxf(sqrtf(sm), 1e-12f);
  __syncthreads();                    // hx reads done
  // publish msg to hx[row][0..31] then assemble xum row into xumL
  #pragma unroll
  for (int j = 0; j < 8; ++j) hx[row * 68 + j0m + j] = f2b(am8[j] * scm);
  __syncthreads();
  {
    u16x8 v0, v1;
    #pragma unroll
    for (int t = 0; t < 16; ++t) {
      const int c = j0 + t;
      unsigned short u;
      if      (c < 3)  u = f2b(sa[c]);
      else if (c < 6)  u = f2b(sa[c - 3]);
      else if (c < 38) u = hx[row * 68 + (c - 6)];
      else if (c == 38) u = f2b(sa[32]);
      else if (c == 39) u = 0x3f80;
      else              u = 0;
      if (t < 8) v0[t] = u; else v1[t - 8] = u;
    }
    unsigned short* dst = &xumL[row * 68 + j0];
    *(u16x8*)dst = v0;
    *(u16x8*)(dst + 8) = v1;
  }
  __syncthreads();                    // xumL complete

  // A-fragments: wave w owns rows w*16..w*16+15 (used as B operand, swapped L1)
  const unsigned short* xr = &xumL[(w * 16 + rl) * 68];
  const bf16x8 af0 = ld8(xr + g * 8);
  const bf16x8 af1 = ld8(xr + 32 + g * 8);
  __syncthreads();                    // af held; h1 may now clobber w0/hx

  const int wm = w >> 2, wn = w & 3;  // layer2: 2 x 64-row bands x 4 x 80-col quarters

  for (int q = 0; q < 2; ++q) {
    f32x4 acc2[4][5];
    #pragma unroll
    for (int mt = 0; mt < 4; ++mt)
      #pragma unroll
      for (int jn = 0; jn < 5; ++jn) acc2[mt][jn] = (f32x4){0.f, 0.f, 0.f, 0.f};

    #pragma unroll
    for (int kh = 0; kh < 2; ++kh) {
      const int NTk = kh ? 12 : 14;   // nt tiles this half (16 cols each)
      const int KSk = kh ? 6 : 7;     // 32-wide k-steps this half
      const int NTO = kh ? 14 : 0;
      const int KSO = kh ? 7 : 0;

      // ---- layer1 (swapped): wave w -> its 16 rows x NTk*16 cols ----
      {
        const unsigned short* w1f = P.img + ((size_t)(q * 312 + NTO * 2)) * 512 + lane * 8;
        unsigned short* h1w = &h1[(size_t)(w * 16 + rl) * H1S + g * 4];
        #pragma unroll 2
        for (int t = 0; t < NTk; ++t) {
          const bf16x8 b0 = ld8(w1f + (size_t)(t * 2) * 512);
          const bf16x8 b1 = ld8(w1f + (size_t)(t * 2 + 1) * 512);
          f32x4 a = (f32x4){0.f, 0.f, 0.f, 0.f};
          a = MFMA(b0, af0, a);
          a = MFMA(b1, af1, a);
          const float c0 = fmaxf(a[0], 0.f), c1 = fmaxf(a[1], 0.f);
          const float c2 = fmaxf(a[2], 0.f), c3 = fmaxf(a[3], 0.f);
          unsigned int p01, p23;
          asm("v_cvt_pk_bf16_f32 %0, %1, %2" : "=v"(p01) : "v"(c0), "v"(c1));
          asm("v_cvt_pk_bf16_f32 %0, %1, %2" : "=v"(p23) : "v"(c2), "v"(c3));
          u32x2 pk; pk[0] = p01; pk[1] = p23;
          *(u32x2*)(h1w + t * 16) = pk;
        }
      }
      __syncthreads();                // h1 half ready

      // ---- layer2: accumulate this half's KSk k-steps ----
      {
        const unsigned short* w2f = P.img + ((size_t)(q * 312 + 52 + wn * 65)) * 512 + lane * 8;
        for (int ks = 0; ks < KSk; ++ks) {
          const int ksg = KSO + ks;
          bf16x8 am[4];
          #pragma unroll
          for (int mt = 0; mt < 4; ++mt)
            am[mt] = ld8(&h1[(size_t)(wm * 64 + mt * 16 + rl) * H1S + ks * 32 + g * 8]);
          #pragma unroll
          for (int jn = 0; jn < 5; ++jn) {
            const bf16x8 b = ld8(w2f + (size_t)(jn * 13 + ksg) * 512);
            #pragma unroll
            for (int mt = 0; mt < 4; ++mt)
              acc2[mt][jn] = MFMA(am[mt], b, acc2[mt][jn]);
          }
        }
      }
      __syncthreads();                // h1 reads done; next half may overwrite
    }

    // ---- epilogue: x = sum_n relu(h2+b2)*w3 + b3 ----
    const float* b2p = q ? P.q2b2 : P.q1b2;
    const float* w3  = q ? P.q2w3 : P.q1w3;
    const float* b3  = q ? P.q2b3 : P.q1b3;
    float xp[4][4];
    #pragma unroll
    for (int mt = 0; mt < 4; ++mt)
      #pragma unroll
      for (int i = 0; i < 4; ++i) xp[mt][i] = 0.f;
    #pragma unroll
    for (int jn = 0; jn < 5; ++jn) {
      const int n = wn * 80 + jn * 16 + rl;
      if (n < 300) {
        const float bv = b2p[n], wv = w3[n];
        #pragma unroll
        for (int mt = 0; mt < 4; ++mt)
          #pragma unroll
          for (int i = 0; i < 4; ++i)
            xp[mt][i] += fmaxf(acc2[mt][jn][i] + bv, 0.f) * wv;
      }
    }
    #pragma unroll
    for (int off = 1; off < 16; off <<= 1)
      #pragma unroll
      for (int mt = 0; mt < 4; ++mt)
        #pragma unroll
        for (int i = 0; i < 4; ++i)
          xp[mt][i] += __shfl_xor(xp[mt][i], off, 64);
    if (rl == 0) {
      #pragma unroll
      for (int mt = 0; mt < 4; ++mt)
        #pragma unroll
        for (int i = 0; i < 4; ++i)
          xred[(wm * 64 + mt * 16 + g * 4 + i) * 4 + wn] = xp[mt][i];
    }
    __syncthreads();                  // xred visible
    if (tid < TBROWS) {
      const float4 xv = *(const float4*)&xred[tid * 4];
      P.out[(size_t)q * BTOT + (size_t)blockIdx.x * TBROWS + tid] =
          xv.x + xv.y + xv.z + xv.w + b3[0];
    }
    __syncthreads();                  // xred reads done before next q's write
  }
}

extern "C" void kernel_launch(void* const* d_in, const int* in_sizes, int n_in,
                              void* d_out, int out_size, void* d_ws, size_t ws_size,
                              hipStream_t stream) {
  (void)in_sizes; (void)n_in; (void)out_size; (void)ws_size;
  PackP K;
  K.q1w1 = (const float*)d_in[10]; K.q1b1 = (const float*)d_in[11]; K.q1w2 = (const float*)d_in[12];
  K.q2w1 = (const float*)d_in[16]; K.q2b1 = (const float*)d_in[17]; K.q2w2 = (const float*)d_in[18];
  K.ws   = (unsigned short*)d_ws;
  pack_weights<<<dim3(78), dim3(512), 0, stream>>>(K);

  FP P;
  P.state  = (const float*)d_in[0];
  P.action = (const float*)d_in[1];
  P.f1w = (const float*)d_in[2]; P.f1b = (const float*)d_in[3];
  P.f2w = (const float*)d_in[4]; P.f2b = (const float*)d_in[5];
  P.f3w = (const float*)d_in[6]; P.f3b = (const float*)d_in[7];
  P.img  = (const unsigned short*)d_ws;
  P.q1b2 = (const float*)d_in[13]; P.q1w3 = (const float*)d_in[14]; P.q1b3 = (const float*)d_in[15];
  P.q2b2 = (const float*)d_in[19]; P.q2w3 = (const float*)d_in[20]; P.q2b3 = (const float*)d_in[21];
  P.out  = (float*)d_out;
  critic_fused<<<dim3(NBLK), dim3(NTHR), 0, stream>>>(P);
}

// Round 15
// 115.851 us; speedup vs baseline: 1.9784x; 1.1152x over previous
//
#include <hip/hip_runtime.h>
#include <math.h>

// CriticGraphPolicy, MI355X (gfx950). Round 15.
// R14 post-mortem: fusion re-spilled (WRITE 33MB) and scratch blocked the 2nd
// block -> co-residency never happened. R15 keeps R12's split and gets
// co-residency the cheap way: mlp ML_ROWS 128->64 => h1 [64][428] = 54.8KB,
// total LDS 55.8KB -> 2 independent blocks/CU (16 waves/CU, no shared
// barrier between them -> m114 cross-block overlap). R13's PURE ablation
// showed a ~4x TLP gap at 8 waves/CU with zero memory traffic.

#define BTOT   65536
#define XUM_OFF 655360ull        // xum offset in d_ws (frag img = 638,976 B)

// phase0 (+fused pack) -- unchanged from R12
#define PK_BLK  78
#define PH_THR  512
#define PH_ROWS 128
#define PH_BLK  (BTOT / PH_ROWS)
#define F1W 0
#define F1B 2112
#define F2W 2176
#define F2B 6272
#define F3W 6336
#define F3B 8384
#define W0_FLOATS 8416

// mlp: 64 rows/block, 1024 blocks, 8 waves
#define ML_THR  512
#define ML_ROWS 64
#define ML_BLK  (BTOT / ML_ROWS) // 1024
#define H1S     428              // u16 stride: 856B rows -> 2-way banks

typedef float  f32x4 __attribute__((ext_vector_type(4)));
typedef __bf16 bf16x8 __attribute__((ext_vector_type(8)));
typedef unsigned short u16x8 __attribute__((ext_vector_type(8)));
typedef unsigned short u16x4 __attribute__((ext_vector_type(4)));
typedef unsigned int   u32x2 __attribute__((ext_vector_type(2)));

__device__ __forceinline__ unsigned short f2b(float f) {
  union { float f; unsigned int u; } v; v.f = f;
  return (unsigned short)((v.u + 0x7fffu + ((v.u >> 16) & 1u)) >> 16);
}
__device__ __forceinline__ float b2f(unsigned short u) {
  union { unsigned int u; float f; } v; v.u = ((unsigned int)u) << 16;
  return v.f;
}
__device__ __forceinline__ f32x4 MFMA(bf16x8 a, bf16x8 b, f32x4 c) {
  return __builtin_amdgcn_mfma_f32_16x16x32_bf16(a, b, c, 0, 0, 0);
}
__device__ __forceinline__ bf16x8 ld8(const unsigned short* p) {
  return __builtin_bit_cast(bf16x8, *(const u16x8*)p);
}
__device__ __forceinline__ float ftanh(float x) {
  float e = __builtin_amdgcn_exp2f(x * 2.885390081777927f);
  return (e - 1.0f) * __builtin_amdgcn_rcpf(e + 1.0f);
}

// ---------------- phase0 kernel (+fused fragment pack) -- unchanged R12 -----
struct P0 {
  const float* state; const float* action;
  const float* f1w; const float* f1b;
  const float* f2w; const float* f2b;
  const float* f3w; const float* f3b;
  const float* q1w1; const float* q1b1; const float* q1w2;
  const float* q2w1; const float* q2b1; const float* q2w2;
  unsigned short* ws;
  unsigned short* xum;
};

__global__ __launch_bounds__(PH_THR, 4) void phase0_kernel(P0 P) {
  __shared__ float w0[W0_FLOATS];
  __shared__ unsigned short hx[PH_ROWS * 68];
  const int tid = threadIdx.x;

  if (blockIdx.x < PK_BLK) {          // fragment pack path
    const int gid = blockIdx.x * PH_THR + tid;
    const int lane = gid & 63, f = gid >> 6;
    const int q = f / 312, fl = f - q * 312;
    const float* w1 = q ? P.q2w1 : P.q1w1;
    const float* b1 = q ? P.q2b1 : P.q1b1;
    const float* w2 = q ? P.q2w2 : P.q1w2;
    int nt, ks; const bool isw1 = (fl < 52);
    if (isw1) { nt = fl >> 1; ks = fl & 1; }
    else      { int fl2 = fl - 52; nt = fl2 / 13; ks = fl2 - nt * 13; }
    const int col = nt * 16 + (lane & 15);
    const int k0  = ks * 32 + (lane >> 4) * 8;
    unsigned short v[8];
    #pragma unroll
    for (int j = 0; j < 8; ++j) {
      const int k = k0 + j;
      float x = 0.f;
      if (isw1) {
        if (col < 400) {
          if (k < 39) x = w1[(6 + k) * 400 + col];
          else if (k == 39) x = b1[col];
        }
      } else {
        if (k < 400 && col < 300) x = w2[k * 300 + col];
      }
      v[j] = f2b(x);
    }
    *(u16x8*)(P.ws + (size_t)f * 512 + lane * 8) = *(const u16x8*)v;
    return;
  }

  const int row = tid >> 2, sub = tid & 3, j0 = sub * 16;
  const long grow = (long)(blockIdx.x - PK_BLK) * PH_ROWS + row;

  for (int i = tid; i < 528;  i += PH_THR) *(f32x4*)(w0 + F1W + 4*i) = *(const f32x4*)(P.f1w + 4*i);
  for (int i = tid; i < 16;   i += PH_THR) *(f32x4*)(w0 + F1B + 4*i) = *(const f32x4*)(P.f1b + 4*i);
  for (int i = tid; i < 1024; i += PH_THR) *(f32x4*)(w0 + F2W + 4*i) = *(const f32x4*)(P.f2w + 4*i);
  for (int i = tid; i < 16;   i += PH_THR) *(f32x4*)(w0 + F2B + 4*i) = *(const f32x4*)(P.f2b + 4*i);
  for (int i = tid; i < 512;  i += PH_THR) *(f32x4*)(w0 + F3W + 4*i) = *(const f32x4*)(P.f3w + 4*i);
  for (int i = tid; i < 8;    i += PH_THR) *(f32x4*)(w0 + F3B + 4*i) = *(const f32x4*)(P.f3b + 4*i);

  float sa[33];
  {
    const float4* sp = (const float4*)(P.state + grow * 32);
    #pragma unroll
    for (int c = 0; c < 8; ++c) {
      float4 v = sp[c];
      sa[c*4+0] = v.x; sa[c*4+1] = v.y; sa[c*4+2] = v.z; sa[c*4+3] = v.w;
    }
    sa[32] = P.action[grow];
  }
  __syncthreads();

  float acc[16];
  #pragma unroll
  for (int j = 0; j < 16; ++j) acc[j] = w0[F1B + j0 + j];
  #pragma unroll 4
  for (int i = 0; i < 33; ++i) {
    const float s = sa[i];
    const f32x4* wr = (const f32x4*)&w0[F1W + i * 64 + j0];
    #pragma unroll
    for (int c = 0; c < 4; ++c) {
      f32x4 wv = wr[c];
      acc[c*4+0] += s * wv[0]; acc[c*4+1] += s * wv[1];
      acc[c*4+2] += s * wv[2]; acc[c*4+3] += s * wv[3];
    }
  }
  {
    float ss = 0.f;
    #pragma unroll
    for (int j = 0; j < 16; ++j) ss += acc[j] * acc[j];
    ss += __shfl_xor(ss, 1, 64); ss += __shfl_xor(ss, 2, 64);
    const float sc = 1.f / fmaxf(sqrtf(ss), 1e-12f);
    #pragma unroll
    for (int j = 0; j < 16; ++j) hx[row * 68 + j0 + j] = f2b(ftanh(acc[j] * sc));
  }
  __syncthreads();
  #pragma unroll
  for (int j = 0; j < 16; ++j) acc[j] = w0[F2B + j0 + j];
  #pragma unroll 4
  for (int i0 = 0; i0 < 16; ++i0) {
    const u16x4 hv4 = *(const u16x4*)&hx[row * 68 + i0 * 4];
    #pragma unroll
    for (int u = 0; u < 4; ++u) {
      const float hv = b2f(hv4[u]);
      const f32x4* wr = (const f32x4*)&w0[F2W + (i0 * 4 + u) * 64 + j0];
      #pragma unroll
      for (int c = 0; c < 4; ++c) {
        f32x4 wv = wr[c];
        acc[c*4+0] += hv * wv[0]; acc[c*4+1] += hv * wv[1];
        acc[c*4+2] += hv * wv[2]; acc[c*4+3] += hv * wv[3];
      }
    }
  }
  __syncthreads();
  #pragma unroll
  for (int j = 0; j < 16; ++j) hx[row * 68 + j0 + j] = f2b(ftanh(acc[j]));
  __syncthreads();
  const int j0m = sub * 8;
  float am[8];
  #pragma unroll
  for (int j = 0; j < 8; ++j) am[j] = w0[F3B + j0m + j];
  #pragma unroll 4
  for (int i0 = 0; i0 < 16; ++i0) {
    const u16x4 hv4 = *(const u16x4*)&hx[row * 68 + i0 * 4];
    #pragma unroll
    for (int u = 0; u < 4; ++u) {
      const float hv = b2f(hv4[u]);
      const f32x4* wr = (const f32x4*)&w0[F3W + (i0 * 4 + u) * 32 + j0m];
      #pragma unroll
      for (int c = 0; c < 2; ++c) {
        f32x4 wv = wr[c];
        am[c*4+0] += hv * wv[0]; am[c*4+1] += hv * wv[1];
        am[c*4+2] += hv * wv[2]; am[c*4+3] += hv * wv[3];
      }
    }
  }
  float sm = 0.f;
  #pragma unroll
  for (int j = 0; j < 8; ++j) sm += am[j] * am[j];
  sm += __shfl_xor(sm, 1, 64); sm += __shfl_xor(sm, 2, 64);
  const float scm = 1.f / fmaxf(sqrtf(sm), 1e-12f);
  __syncthreads();
  #pragma unroll
  for (int j = 0; j < 8; ++j) hx[row * 68 + j0m + j] = f2b(am[j] * scm);
  __syncthreads();
  {
    u16x8 v0, v1;
    #pragma unroll
    for (int t = 0; t < 16; ++t) {
      const int c = j0 + t;
      unsigned short u;
      if      (c < 3)  u = f2b(sa[c]);
      else if (c < 6)  u = f2b(sa[c - 3]);
      else if (c < 38) u = hx[row * 68 + (c - 6)];
      else if (c == 38) u = f2b(sa[32]);
      else if (c == 39) u = 0x3f80;
      else              u = 0;
      if (t < 8) v0[t] = u; else v1[t - 8] = u;
    }
    unsigned short* dst = P.xum + (size_t)grow * 64 + j0;
    *(u16x8*)dst = v0;
    *(u16x8*)(dst + 8) = v1;
  }
}

// ---------------- mlp kernel: 64 rows/block -> 2 blocks/CU ----------------
struct P1 {
  const unsigned short* img; const unsigned short* xum;
  const float* q1b2; const float* q1w3; const float* q1b3;
  const float* q2b2; const float* q2w3; const float* q2b3;
  float* out;
};

__global__ __launch_bounds__(ML_THR, 2) void mlp_kernel(P1 P) {
  __shared__ __align__(16) unsigned short h1[ML_ROWS * H1S]; // 54,784 B
  __shared__ float xred[ML_ROWS * 4];                        //  1,024 B

  const int tid  = threadIdx.x;
  const int lane = tid & 63, w = tid >> 6;        // 8 waves
  const int rl = lane & 15, g = lane >> 4;

  const int r1 = w & 3, ch = w >> 2;              // layer1: 4 row-tiles x 2 col-halves
  const int wm = w >> 2, wn = w & 3;              // layer2: 2 x 32-row bands x 4 quarters

  // xum A-fragments (global, coalesced; B operand of swapped layer1)
  const unsigned short* xr = P.xum + ((size_t)blockIdx.x * ML_ROWS + r1 * 16 + rl) * 64;
  const bf16x8 af0 = ld8(xr + g * 8);
  const bf16x8 af1 = ld8(xr + 32 + g * 8);

  for (int q = 0; q < 2; ++q) {
    // ---- layer1 (swapped): wave -> 16 rows x 208 cols; one b64 store/t ----
    {
      const unsigned short* w1f = P.img + ((size_t)(q * 312 + ch * 26)) * 512 + lane * 8;
      unsigned short* h1w = &h1[(size_t)(r1 * 16 + rl) * H1S + ch * 208 + g * 4];
      #pragma unroll 2
      for (int t = 0; t < 13; ++t) {
        const bf16x8 b0 = ld8(w1f + (size_t)(t * 2) * 512);
        const bf16x8 b1 = ld8(w1f + (size_t)(t * 2 + 1) * 512);
        f32x4 a = (f32x4){0.f, 0.f, 0.f, 0.f};
        a = MFMA(b0, af0, a);
        a = MFMA(b1, af1, a);
        const float c0 = fmaxf(a[0], 0.f), c1 = fmaxf(a[1], 0.f);
        const float c2 = fmaxf(a[2], 0.f), c3 = fmaxf(a[3], 0.f);
        unsigned int p01, p23;
        asm("v_cvt_pk_bf16_f32 %0, %1, %2" : "=v"(p01) : "v"(c0), "v"(c1));
        asm("v_cvt_pk_bf16_f32 %0, %1, %2" : "=v"(p23) : "v"(c2), "v"(c3));
        u32x2 pk; pk[0] = p01; pk[1] = p23;
        *(u32x2*)(h1w + t * 16) = pk;
      }
    }
    __syncthreads();                              // h1 complete

    // ---- layer2: rows wm*32..+31 x cols wn*80..+79, K=416 ----
    f32x4 acc2[2][5];
    #pragma unroll
    for (int mt = 0; mt < 2; ++mt)
      #pragma unroll
      for (int jn = 0; jn < 5; ++jn) acc2[mt][jn] = (f32x4){0.f, 0.f, 0.f, 0.f};
    {
      const unsigned short* w2f = P.img + ((size_t)(q * 312 + 52 + wn * 65)) * 512 + lane * 8;
      #pragma unroll 2
      for (int ks = 0; ks < 13; ++ks) {
        const bf16x8 a0 = ld8(&h1[(size_t)(wm * 32 + rl) * H1S + ks * 32 + g * 8]);
        const bf16x8 a1 = ld8(&h1[(size_t)(wm * 32 + 16 + rl) * H1S + ks * 32 + g * 8]);
        #pragma unroll
        for (int jn = 0; jn < 5; ++jn) {
          const bf16x8 b = ld8(w2f + (size_t)(jn * 13 + ks) * 512);
          acc2[0][jn] = MFMA(a0, b, acc2[0][jn]);
          acc2[1][jn] = MFMA(a1, b, acc2[1][jn]);
        }
      }
    }

    // ---- epilogue ----
    const float* b2p = q ? P.q2b2 : P.q1b2;
    const float* w3  = q ? P.q2w3 : P.q1w3;
    const float* b3  = q ? P.q2b3 : P.q1b3;
    float xp[2][4];
    #pragma unroll
    for (int mt = 0; mt < 2; ++mt)
      #pragma unroll
      for (int i = 0; i < 4; ++i) xp[mt][i] = 0.f;
    #pragma unroll
    for (int jn = 0; jn < 5; ++jn) {
      const int n = wn * 80 + jn * 16 + rl;
      if (n < 300) {
        const float bv = b2p[n], wv = w3[n];
        #pragma unroll
        for (int mt = 0; mt < 2; ++mt)
          #pragma unroll
          for (int i = 0; i < 4; ++i)
            xp[mt][i] += fmaxf(acc2[mt][jn][i] + bv, 0.f) * wv;
      }
    }
    #pragma unroll
    for (int off = 1; off < 16; off <<= 1)
      #pragma unroll
      for (int mt = 0; mt < 2; ++mt)
        #pragma unroll
        for (int i = 0; i < 4; ++i)
          xp[mt][i] += __shfl_xor(xp[mt][i], off, 64);
    if (rl == 0) {
      #pragma unroll
      for (int mt = 0; mt < 2; ++mt)
        #pragma unroll
        for (int i = 0; i < 4; ++i)
          xred[(wm * 32 + mt * 16 + g * 4 + i) * 4 + wn] = xp[mt][i];
    }
    __syncthreads();                              // xred visible; h1 reads done
    if (tid < ML_ROWS) {
      const float4 xv = *(const float4*)&xred[tid * 4];
      P.out[(size_t)q * BTOT + (size_t)blockIdx.x * ML_ROWS + tid] =
          xv.x + xv.y + xv.z + xv.w + b3[0];
    }
    __syncthreads();                              // xred read done; h1 reusable
  }
}

extern "C" void kernel_launch(void* const* d_in, const int* in_sizes, int n_in,
                              void* d_out, int out_size, void* d_ws, size_t ws_size,
                              hipStream_t stream) {
  (void)in_sizes; (void)n_in; (void)out_size; (void)ws_size;
  P0 A;
  A.state  = (const float*)d_in[0];
  A.action = (const float*)d_in[1];
  A.f1w = (const float*)d_in[2]; A.f1b = (const float*)d_in[3];
  A.f2w = (const float*)d_in[4]; A.f2b = (const float*)d_in[5];
  A.f3w = (const float*)d_in[6]; A.f3b = (const float*)d_in[7];
  A.q1w1 = (const float*)d_in[10]; A.q1b1 = (const float*)d_in[11]; A.q1w2 = (const float*)d_in[12];
  A.q2w1 = (const float*)d_in[16]; A.q2b1 = (const float*)d_in[17]; A.q2w2 = (const float*)d_in[18];
  A.ws  = (unsigned short*)d_ws;
  A.xum = (unsigned short*)((unsigned char*)d_ws + XUM_OFF);
  phase0_kernel<<<dim3(PK_BLK + PH_BLK), dim3(PH_THR), 0, stream>>>(A);

  P1 B;
  B.img  = (const unsigned short*)d_ws;
  B.xum  = (const unsigned short*)((unsigned char*)d_ws + XUM_OFF);
  B.q1b2 = (const float*)d_in[13]; B.q1w3 = (const float*)d_in[14]; B.q1b3 = (const float*)d_in[15];
  B.q2b2 = (const float*)d_in[19]; B.q2w3 = (const float*)d_in[20]; B.q2b3 = (const float*)d_in[21];
  B.out  = (float*)d_out;
  mlp_kernel<<<dim3(ML_BLK), dim3(ML_THR), 0, stream>>>(B);
}

// Round 16
// 108.216 us; speedup vs baseline: 2.1180x; 1.0706x over previous
//
#include <hip/hip_runtime.h>
#include <math.h>

// CriticGraphPolicy, MI355X (gfx950). Round 16.
// R15 post-mortem: occupancy 2x -> slower (2x blocks duplicated weight
// loads). Refuted so far: VALU, latency, bytes, memory-source, TLP. The
// uncut invariant: per-wave instruction count. R16: mfma_f32_32x32x16
// (2x FLOP/inst, m119's fastest shape), 128 rows/block, N padded to 384
// (12 col-tiles / 4 groups). Layer2 per wave: 52 LDS + 78 loads + 156 MFMA
// vs R12's 52+65+260. Pack emits 32x32x16 fragments (728 x 1KB).

#define BTOT   65536
#define XUM_OFF 745472ull        // frag img = 728*1024 B

// phase0 (+fused pack)
#define PK_BLK  91               // 91*512 = 46592 = 728 frags * 64 lanes
#define PH_THR  512
#define PH_ROWS 128
#define PH_BLK  (BTOT / PH_ROWS)
#define F1W 0
#define F1B 2112
#define F2W 2176
#define F2B 6272
#define F3W 6336
#define F3B 8384
#define W0_FLOATS 8416

// mlp
#define ML_THR  512
#define ML_ROWS 128
#define ML_BLK  (BTOT / ML_ROWS) // 512
#define H1S     424              // u16 stride (848B rows, 16B-aligned)
#define NFQ     364              // frags per q-net: w1 52 + w2 312

typedef float  f32x4  __attribute__((ext_vector_type(4)));
typedef float  f32x16 __attribute__((ext_vector_type(16)));
typedef __bf16 bf16x8 __attribute__((ext_vector_type(8)));
typedef unsigned short u16x8 __attribute__((ext_vector_type(8)));
typedef unsigned short u16x4 __attribute__((ext_vector_type(4)));
typedef unsigned int   u32x2 __attribute__((ext_vector_type(2)));

__device__ __forceinline__ unsigned short f2b(float f) {
  union { float f; unsigned int u; } v; v.f = f;
  return (unsigned short)((v.u + 0x7fffu + ((v.u >> 16) & 1u)) >> 16);
}
__device__ __forceinline__ float b2f(unsigned short u) {
  union { unsigned int u; float f; } v; v.u = ((unsigned int)u) << 16;
  return v.f;
}
__device__ __forceinline__ f32x16 MFMA32(bf16x8 a, bf16x8 b, f32x16 c) {
  return __builtin_amdgcn_mfma_f32_32x32x16_bf16(a, b, c, 0, 0, 0);
}
__device__ __forceinline__ bf16x8 ld8(const unsigned short* p) {
  return __builtin_bit_cast(bf16x8, *(const u16x8*)p);
}
__device__ __forceinline__ float ftanh(float x) {
  float e = __builtin_amdgcn_exp2f(x * 2.885390081777927f);
  return (e - 1.0f) * __builtin_amdgcn_rcpf(e + 1.0f);
}

// ---------------- phase0 kernel (+fused 32x32x16 fragment pack) -------------
// frag f < 728: q = f/364, fl = f%364.
//  fl<52  -> w1eff frag (ct=fl>>2, kst=fl&3):  elem[lane][j] =
//            W1eff[kst*16+(lane>>5)*8+j][ct*32+(lane&31)]  (c pad 416)
//  fl>=52 -> w2 frag (fl2=fl-52; ct=fl2/26, kst=fl2%26): elem[lane][j] =
//            w2[kst*16+(lane>>5)*8+j][ct*32+(lane&31)]  (k pad 416, c pad 384)
struct P0 {
  const float* state; const float* action;
  const float* f1w; const float* f1b;
  const float* f2w; const float* f2b;
  const float* f3w; const float* f3b;
  const float* q1w1; const float* q1b1; const float* q1w2;
  const float* q2w1; const float* q2b1; const float* q2w2;
  unsigned short* ws;
  unsigned short* xum;
};

__global__ __launch_bounds__(PH_THR, 4) void phase0_kernel(P0 P) {
  __shared__ float w0[W0_FLOATS];
  __shared__ unsigned short hx[PH_ROWS * 68];
  const int tid = threadIdx.x;

  if (blockIdx.x < PK_BLK) {          // ---- fragment pack path ----
    const int gid = blockIdx.x * PH_THR + tid;   // < 46592 exactly
    const int lane = gid & 63, f = gid >> 6;
    const int q = f / NFQ, fl = f - q * NFQ;
    const float* w1 = q ? P.q2w1 : P.q1w1;
    const float* b1 = q ? P.q2b1 : P.q1b1;
    const float* w2 = q ? P.q2w2 : P.q1w2;
    int ct, kst; const bool isw1 = (fl < 52);
    if (isw1) { ct = fl >> 2; kst = fl & 3; }
    else      { int fl2 = fl - 52; ct = fl2 / 26; kst = fl2 - ct * 26; }
    const int col = ct * 32 + (lane & 31);
    const int k0  = kst * 16 + (lane >> 5) * 8;
    unsigned short v[8];
    #pragma unroll
    for (int j = 0; j < 8; ++j) {
      const int k = k0 + j;
      float x = 0.f;
      if (isw1) {
        if (col < 400) {
          if (k < 39) x = w1[(6 + k) * 400 + col];
          else if (k == 39) x = b1[col];
        }
      } else {
        if (k < 400 && col < 300) x = w2[k * 300 + col];
      }
      v[j] = f2b(x);
    }
    *(u16x8*)(P.ws + (size_t)f * 512 + lane * 8) = *(const u16x8*)v;
    return;
  }

  // ---- feature-MLP path (unchanged from R12) ----
  const int row = tid >> 2, sub = tid & 3, j0 = sub * 16;
  const long grow = (long)(blockIdx.x - PK_BLK) * PH_ROWS + row;

  for (int i = tid; i < 528;  i += PH_THR) *(f32x4*)(w0 + F1W + 4*i) = *(const f32x4*)(P.f1w + 4*i);
  for (int i = tid; i < 16;   i += PH_THR) *(f32x4*)(w0 + F1B + 4*i) = *(const f32x4*)(P.f1b + 4*i);
  for (int i = tid; i < 1024; i += PH_THR) *(f32x4*)(w0 + F2W + 4*i) = *(const f32x4*)(P.f2w + 4*i);
  for (int i = tid; i < 16;   i += PH_THR) *(f32x4*)(w0 + F2B + 4*i) = *(const f32x4*)(P.f2b + 4*i);
  for (int i = tid; i < 512;  i += PH_THR) *(f32x4*)(w0 + F3W + 4*i) = *(const f32x4*)(P.f3w + 4*i);
  for (int i = tid; i < 8;    i += PH_THR) *(f32x4*)(w0 + F3B + 4*i) = *(const f32x4*)(P.f3b + 4*i);

  float sa[33];
  {
    const float4* sp = (const float4*)(P.state + grow * 32);
    #pragma unroll
    for (int c = 0; c < 8; ++c) {
      float4 v = sp[c];
      sa[c*4+0] = v.x; sa[c*4+1] = v.y; sa[c*4+2] = v.z; sa[c*4+3] = v.w;
    }
    sa[32] = P.action[grow];
  }
  __syncthreads();

  float acc[16];
  #pragma unroll
  for (int j = 0; j < 16; ++j) acc[j] = w0[F1B + j0 + j];
  #pragma unroll 4
  for (int i = 0; i < 33; ++i) {
    const float s = sa[i];
    const f32x4* wr = (const f32x4*)&w0[F1W + i * 64 + j0];
    #pragma unroll
    for (int c = 0; c < 4; ++c) {
      f32x4 wv = wr[c];
      acc[c*4+0] += s * wv[0]; acc[c*4+1] += s * wv[1];
      acc[c*4+2] += s * wv[2]; acc[c*4+3] += s * wv[3];
    }
  }
  {
    float ss = 0.f;
    #pragma unroll
    for (int j = 0; j < 16; ++j) ss += acc[j] * acc[j];
    ss += __shfl_xor(ss, 1, 64); ss += __shfl_xor(ss, 2, 64);
    const float sc = 1.f / fmaxf(sqrtf(ss), 1e-12f);
    #pragma unroll
    for (int j = 0; j < 16; ++j) hx[row * 68 + j0 + j] = f2b(ftanh(acc[j] * sc));
  }
  __syncthreads();
  #pragma unroll
  for (int j = 0; j < 16; ++j) acc[j] = w0[F2B + j0 + j];
  #pragma unroll 4
  for (int i0 = 0; i0 < 16; ++i0) {
    const u16x4 hv4 = *(const u16x4*)&hx[row * 68 + i0 * 4];
    #pragma unroll
    for (int u = 0; u < 4; ++u) {
      const float hv = b2f(hv4[u]);
      const f32x4* wr = (const f32x4*)&w0[F2W + (i0 * 4 + u) * 64 + j0];
      #pragma unroll
      for (int c = 0; c < 4; ++c) {
        f32x4 wv = wr[c];
        acc[c*4+0] += hv * wv[0]; acc[c*4+1] += hv * wv[1];
        acc[c*4+2] += hv * wv[2]; acc[c*4+3] += hv * wv[3];
      }
    }
  }
  __syncthreads();
  #pragma unroll
  for (int j = 0; j < 16; ++j) hx[row * 68 + j0 + j] = f2b(ftanh(acc[j]));
  __syncthreads();
  const int j0m = sub * 8;
  float am[8];
  #pragma unroll
  for (int j = 0; j < 8; ++j) am[j] = w0[F3B + j0m + j];
  #pragma unroll 4
  for (int i0 = 0; i0 < 16; ++i0) {
    const u16x4 hv4 = *(const u16x4*)&hx[row * 68 + i0 * 4];
    #pragma unroll
    for (int u = 0; u < 4; ++u) {
      const float hv = b2f(hv4[u]);
      const f32x4* wr = (const f32x4*)&w0[F3W + (i0 * 4 + u) * 32 + j0m];
      #pragma unroll
      for (int c = 0; c < 2; ++c) {
        f32x4 wv = wr[c];
        am[c*4+0] += hv * wv[0]; am[c*4+1] += hv * wv[1];
        am[c*4+2] += hv * wv[2]; am[c*4+3] += hv * wv[3];
      }
    }
  }
  float sm = 0.f;
  #pragma unroll
  for (int j = 0; j < 8; ++j) sm += am[j] * am[j];
  sm += __shfl_xor(sm, 1, 64); sm += __shfl_xor(sm, 2, 64);
  const float scm = 1.f / fmaxf(sqrtf(sm), 1e-12f);
  __syncthreads();
  #pragma unroll
  for (int j = 0; j < 8; ++j) hx[row * 68 + j0m + j] = f2b(am[j] * scm);
  __syncthreads();
  {
    u16x8 v0, v1;
    #pragma unroll
    for (int t = 0; t < 16; ++t) {
      const int c = j0 + t;
      unsigned short u;
      if      (c < 3)  u = f2b(sa[c]);
      else if (c < 6)  u = f2b(sa[c - 3]);
      else if (c < 38) u = hx[row * 68 + (c - 6)];
      else if (c == 38) u = f2b(sa[32]);
      else if (c == 39) u = 0x3f80;
      else              u = 0;
      if (t < 8) v0[t] = u; else v1[t - 8] = u;
    }
    unsigned short* dst = P.xum + (size_t)grow * 64 + j0;
    *(u16x8*)dst = v0;
    *(u16x8*)(dst + 8) = v1;
  }
}

// ---------------- mlp kernel: 32x32x16 MFMAs ----------------
struct P1 {
  const unsigned short* img; const unsigned short* xum;
  const float* q1b2; const float* q1w3; const float* q1b3;
  const float* q2b2; const float* q2w3; const float* q2b3;
  float* out;
};

__global__ __launch_bounds__(ML_THR, 2) void mlp_kernel(P1 P) {
  __shared__ __align__(16) unsigned short h1[ML_ROWS * H1S]; // 108,544 B
  __shared__ float xred[ML_ROWS * 4];

  const int tid  = threadIdx.x;
  const int lane = tid & 63, w = tid >> 6;        // 8 waves
  const int l31 = lane & 31, g2 = lane >> 5;

  // layer1: wave -> row-band rb (32 rows), col-half ch (7 or 6 of 13 ct)
  const int rb = w & 3, ch = w >> 2;
  const int ct0 = ch ? 7 : 0, ctN = ch ? 6 : 7;
  // layer2: wave -> rb-pair rbh (64 rows), col-group cg (3 ct of 12)
  const int rbh = w >> 2, cg = w & 3;

  // xum fragments for layer1 (B operand; rb fixed per wave) -- load once
  bf16x8 xf[4];
  {
    const unsigned short* xr =
        P.xum + ((size_t)blockIdx.x * ML_ROWS + rb * 32 + l31) * 64 + g2 * 8;
    #pragma unroll
    for (int kst = 0; kst < 4; ++kst) xf[kst] = ld8(xr + kst * 16);
  }

  for (int q = 0; q < 2; ++q) {
    // ---- layer1 (swapped): h1[r][c] = relu(xum @ W1eff), bias folded ----
    for (int t = 0; t < ctN; ++t) {
      const int ct = ct0 + t;
      const unsigned short* wf = P.img + ((size_t)(q * NFQ + ct * 4)) * 512 + lane * 8;
      f32x16 a = {};
      #pragma unroll
      for (int kst = 0; kst < 4; ++kst)
        a = MFMA32(ld8(wf + (size_t)kst * 512), xf[kst], a);
      // D: col(lane&31)=batch row r; row(regs)=w1 col c = (reg&3)+8*(reg>>2)+4*g2
      unsigned short* h1w = &h1[(size_t)(rb * 32 + l31) * H1S + ct * 32 + 4 * g2];
      #pragma unroll
      for (int grp = 0; grp < 4; ++grp) {
        const float c0 = fmaxf(a[grp*4+0], 0.f), c1 = fmaxf(a[grp*4+1], 0.f);
        const float c2 = fmaxf(a[grp*4+2], 0.f), c3 = fmaxf(a[grp*4+3], 0.f);
        unsigned int p01, p23;
        asm("v_cvt_pk_bf16_f32 %0, %1, %2" : "=v"(p01) : "v"(c0), "v"(c1));
        asm("v_cvt_pk_bf16_f32 %0, %1, %2" : "=v"(p23) : "v"(c2), "v"(c3));
        u32x2 pk; pk[0] = p01; pk[1] = p23;
        *(u32x2*)(h1w + grp * 8) = pk;            // cols ct*32 + grp*8 + 4g2 + 0..3
      }
    }
    __syncthreads();                              // h1 complete

    // ---- layer2: rows rbh*64..+63 x cols cg*96..+95, K=416 (26 ksteps) ----
    f32x16 acc0[3], acc1[3];
    #pragma unroll
    for (int t = 0; t < 3; ++t) { acc0[t] = (f32x16){}; acc1[t] = (f32x16){}; }
    {
      const unsigned short* w2f =
          P.img + ((size_t)(q * NFQ + 52 + cg * 3 * 26)) * 512 + lane * 8;
      for (int kst = 0; kst < 26; ++kst) {
        const bf16x8 a0 = ld8(&h1[(size_t)(rbh * 64 + l31) * H1S + kst * 16 + g2 * 8]);
        const bf16x8 a1 = ld8(&h1[(size_t)(rbh * 64 + 32 + l31) * H1S + kst * 16 + g2 * 8]);
        #pragma unroll
        for (int t = 0; t < 3; ++t) {
          const bf16x8 b = ld8(w2f + (size_t)(t * 26 + kst) * 512);
          acc0[t] = MFMA32(a0, b, acc0[t]);
          acc1[t] = MFMA32(a1, b, acc1[t]);
        }
      }
    }

    // ---- epilogue: x = sum_n relu(h2+b2)*w3 + b3 ----
    const float* b2p = q ? P.q2b2 : P.q1b2;
    const float* w3  = q ? P.q2w3 : P.q1w3;
    const float* b3  = q ? P.q2b3 : P.q1b3;
    float xp0[16], xp1[16];
    #pragma unroll
    for (int i = 0; i < 16; ++i) { xp0[i] = 0.f; xp1[i] = 0.f; }
    #pragma unroll
    for (int t = 0; t < 3; ++t) {
      const int n = cg * 96 + t * 32 + l31;
      if (n < 300) {
        const float bv = b2p[n], wv = w3[n];
        #pragma unroll
        for (int i = 0; i < 16; ++i) {
          xp0[i] += fmaxf(acc0[t][i] + bv, 0.f) * wv;
          xp1[i] += fmaxf(acc1[t][i] + bv, 0.f) * wv;
        }
      }
    }
    #pragma unroll
    for (int off = 1; off < 32; off <<= 1)
      #pragma unroll
      for (int i = 0; i < 16; ++i) {
        xp0[i] += __shfl_xor(xp0[i], off, 64);
        xp1[i] += __shfl_xor(xp1[i], off, 64);
      }
    if (l31 == 0) {                               // lanes 0 and 32
      #pragma unroll
      for (int i = 0; i < 16; ++i) {
        const int rl = (i & 3) + 8 * (i >> 2) + 4 * g2;
        xred[(rbh * 64 + rl) * 4 + cg]      = xp0[i];
        xred[(rbh * 64 + 32 + rl) * 4 + cg] = xp1[i];
      }
    }
    __syncthreads();                              // xred visible; h1 reads done
    if (tid < ML_ROWS) {
      const float4 xv = *(const float4*)&xred[tid * 4];
      P.out[(size_t)q * BTOT + (size_t)blockIdx.x * ML_ROWS + tid] =
          xv.x + xv.y + xv.z + xv.w + b3[0];
    }
    __syncthreads();                              // xred read done; h1 reusable
  }
}

extern "C" void kernel_launch(void* const* d_in, const int* in_sizes, int n_in,
                              void* d_out, int out_size, void* d_ws, size_t ws_size,
                              hipStream_t stream) {
  (void)in_sizes; (void)n_in; (void)out_size; (void)ws_size;
  P0 A;
  A.state  = (const float*)d_in[0];
  A.action = (const float*)d_in[1];
  A.f1w = (const float*)d_in[2]; A.f1b = (const float*)d_in[3];
  A.f2w = (const float*)d_in[4]; A.f2b = (const float*)d_in[5];
  A.f3w = (const float*)d_in[6]; A.f3b = (const float*)d_in[7];
  A.q1w1 = (const float*)d_in[10]; A.q1b1 = (const float*)d_in[11]; A.q1w2 = (const float*)d_in[12];
  A.q2w1 = (const float*)d_in[16]; A.q2b1 = (const float*)d_in[17]; A.q2w2 = (const float*)d_in[18];
  A.ws  = (unsigned short*)d_ws;
  A.xum = (unsigned short*)((unsigned char*)d_ws + XUM_OFF);
  phase0_kernel<<<dim3(PK_BLK + PH_BLK), dim3(PH_THR), 0, stream>>>(A);

  P1 B;
  B.img  = (const unsigned short*)d_ws;
  B.xum  = (const unsigned short*)((unsigned char*)d_ws + XUM_OFF);
  B.q1b2 = (const float*)d_in[13]; B.q1w3 = (const float*)d_in[14]; B.q1b3 = (const float*)d_in[15];
  B.q2b2 = (const float*)d_in[19]; B.q2w3 = (const float*)d_in[20]; B.q2b3 = (const float*)d_in[21];
  B.out  = (float*)d_out;
  mlp_kernel<<<dim3(ML_BLK), dim3(ML_THR), 0, stream>>>(B);
}

// Round 17
// 105.136 us; speedup vs baseline: 2.1801x; 1.0293x over previous
//
#include <hip/hip_runtime.h>
#include <math.h>

// CriticGraphPolicy, MI355X (gfx950). Round 17.
// R16 post-mortem: 25% fewer instructions, same time -> mlp's ~80us is this
// decomposition's structural plateau (~524 TF, 21% peak; refuted: VALU,
// latency, bytes, memory(PURE FETCH=0), TLP, inst count). Revert mlp to R12
// (best measured, 77.4us). Attack phase0 instead: it runs at 25% VALU peak
// because fc loops are LDS-read-bound (4x ds_read_b128 per 16 FMAs).
// R17: 2 rows/thread (PH_ROWS 256) -> w0 reads amortized 2x; sa regs die
// after fc1 (pos/action reloaded at assembly); launch_bounds (512,2).

#define BTOT   65536
#define XUM_OFF 655360ull        // xum offset in d_ws (frag img = 638,976 B)

// phase0 (+fused pack)
#define PK_BLK  78
#define PH_THR  512
#define PH_ROWS 256              // 2 rows per thread
#define PH_BLK  (BTOT / PH_ROWS) // 256
#define F1W 0
#define F1B 2112
#define F2W 2176
#define F2B 6272
#define F3W 6336
#define F3B 8384
#define W0_FLOATS 8416

// mlp (R12 verbatim)
#define ML_THR  512
#define ML_ROWS 128
#define ML_BLK  (BTOT / ML_ROWS)
#define H1S     428

typedef float  f32x4 __attribute__((ext_vector_type(4)));
typedef __bf16 bf16x8 __attribute__((ext_vector_type(8)));
typedef unsigned short u16x8 __attribute__((ext_vector_type(8)));
typedef unsigned short u16x4 __attribute__((ext_vector_type(4)));
typedef unsigned int   u32x2 __attribute__((ext_vector_type(2)));

__device__ __forceinline__ unsigned short f2b(float f) {
  union { float f; unsigned int u; } v; v.f = f;
  return (unsigned short)((v.u + 0x7fffu + ((v.u >> 16) & 1u)) >> 16);
}
__device__ __forceinline__ float b2f(unsigned short u) {
  union { unsigned int u; float f; } v; v.u = ((unsigned int)u) << 16;
  return v.f;
}
__device__ __forceinline__ f32x4 MFMA(bf16x8 a, bf16x8 b, f32x4 c) {
  return __builtin_amdgcn_mfma_f32_16x16x32_bf16(a, b, c, 0, 0, 0);
}
__device__ __forceinline__ bf16x8 ld8(const unsigned short* p) {
  return __builtin_bit_cast(bf16x8, *(const u16x8*)p);
}
__device__ __forceinline__ float ftanh(float x) {
  float e = __builtin_amdgcn_exp2f(x * 2.885390081777927f);
  return (e - 1.0f) * __builtin_amdgcn_rcpf(e + 1.0f);
}

// ---------------- phase0 kernel (+fused fragment pack, R12 layout) ----------
struct P0 {
  const float* state; const float* action;
  const float* f1w; const float* f1b;
  const float* f2w; const float* f2b;
  const float* f3w; const float* f3b;
  const float* q1w1; const float* q1b1; const float* q1w2;
  const float* q2w1; const float* q2b1; const float* q2w2;
  unsigned short* ws;
  unsigned short* xum;
};

__global__ __launch_bounds__(PH_THR, 2) void phase0_kernel(P0 P) {
  __shared__ float w0[W0_FLOATS];                  // 33,664 B
  __shared__ unsigned short hx[PH_ROWS * 68];      // 34,816 B  (total 68,480)
  const int tid = threadIdx.x;

  if (blockIdx.x < PK_BLK) {          // ---- fragment pack path (R12) ----
    const int gid = blockIdx.x * PH_THR + tid;
    const int lane = gid & 63, f = gid >> 6;
    const int q = f / 312, fl = f - q * 312;
    const float* w1 = q ? P.q2w1 : P.q1w1;
    const float* b1 = q ? P.q2b1 : P.q1b1;
    const float* w2 = q ? P.q2w2 : P.q1w2;
    int nt, ks; const bool isw1 = (fl < 52);
    if (isw1) { nt = fl >> 1; ks = fl & 1; }
    else      { int fl2 = fl - 52; nt = fl2 / 13; ks = fl2 - nt * 13; }
    const int col = nt * 16 + (lane & 15);
    const int k0  = ks * 32 + (lane >> 4) * 8;
    unsigned short v[8];
    #pragma unroll
    for (int j = 0; j < 8; ++j) {
      const int k = k0 + j;
      float x = 0.f;
      if (isw1) {
        if (col < 400) {
          if (k < 39) x = w1[(6 + k) * 400 + col];
          else if (k == 39) x = b1[col];
        }
      } else {
        if (k < 400 && col < 300) x = w2[k * 300 + col];
      }
      v[j] = f2b(x);
    }
    *(u16x8*)(P.ws + (size_t)f * 512 + lane * 8) = *(const u16x8*)v;
    return;
  }

  // ---- feature-MLP path: thread handles rows rid and rid+128 ----
  const int rid = tid >> 2, sub = tid & 3, j0 = sub * 16;
  const long g0 = (long)(blockIdx.x - PK_BLK) * PH_ROWS + rid;
  const long g1 = g0 + 128;

  for (int i = tid; i < 528;  i += PH_THR) *(f32x4*)(w0 + F1W + 4*i) = *(const f32x4*)(P.f1w + 4*i);
  for (int i = tid; i < 16;   i += PH_THR) *(f32x4*)(w0 + F1B + 4*i) = *(const f32x4*)(P.f1b + 4*i);
  for (int i = tid; i < 1024; i += PH_THR) *(f32x4*)(w0 + F2W + 4*i) = *(const f32x4*)(P.f2w + 4*i);
  for (int i = tid; i < 16;   i += PH_THR) *(f32x4*)(w0 + F2B + 4*i) = *(const f32x4*)(P.f2b + 4*i);
  for (int i = tid; i < 512;  i += PH_THR) *(f32x4*)(w0 + F3W + 4*i) = *(const f32x4*)(P.f3w + 4*i);
  for (int i = tid; i < 8;    i += PH_THR) *(f32x4*)(w0 + F3B + 4*i) = *(const f32x4*)(P.f3b + 4*i);

  // fc1 with both rows' inputs live (sa dies after this section)
  {
    float sa0[33], sa1[33];
    {
      const float4* sp0 = (const float4*)(P.state + g0 * 32);
      const float4* sp1 = (const float4*)(P.state + g1 * 32);
      #pragma unroll
      for (int c = 0; c < 8; ++c) {
        float4 a = sp0[c], b = sp1[c];
        sa0[c*4+0] = a.x; sa0[c*4+1] = a.y; sa0[c*4+2] = a.z; sa0[c*4+3] = a.w;
        sa1[c*4+0] = b.x; sa1[c*4+1] = b.y; sa1[c*4+2] = b.z; sa1[c*4+3] = b.w;
      }
      sa0[32] = P.action[g0];
      sa1[32] = P.action[g1];
    }
    __syncthreads();
    float a0[16], a1[16];
    #pragma unroll
    for (int j = 0; j < 16; ++j) { a0[j] = w0[F1B + j0 + j]; a1[j] = a0[j]; }
    #pragma unroll 4
    for (int i = 0; i < 33; ++i) {
      const float s0 = sa0[i], s1 = sa1[i];
      const f32x4* wr = (const f32x4*)&w0[F1W + i * 64 + j0];
      #pragma unroll
      for (int c = 0; c < 4; ++c) {
        f32x4 wv = wr[c];
        #pragma unroll
        for (int u = 0; u < 4; ++u) {
          a0[c*4+u] += s0 * wv[u];
          a1[c*4+u] += s1 * wv[u];
        }
      }
    }
    float ss0 = 0.f, ss1 = 0.f;
    #pragma unroll
    for (int j = 0; j < 16; ++j) { ss0 += a0[j] * a0[j]; ss1 += a1[j] * a1[j]; }
    ss0 += __shfl_xor(ss0, 1, 64); ss0 += __shfl_xor(ss0, 2, 64);
    ss1 += __shfl_xor(ss1, 1, 64); ss1 += __shfl_xor(ss1, 2, 64);
    const float sc0 = 1.f / fmaxf(sqrtf(ss0), 1e-12f);
    const float sc1 = 1.f / fmaxf(sqrtf(ss1), 1e-12f);
    #pragma unroll
    for (int j = 0; j < 16; ++j) {
      hx[rid * 68 + j0 + j]        = f2b(ftanh(a0[j] * sc0));
      hx[(rid + 128) * 68 + j0 + j] = f2b(ftanh(a1[j] * sc1));
    }
  }
  __syncthreads();
  // fc2: h2 = tanh(h @ w2[0:64] + b2), both rows share w-reads
  {
    float a0[16], a1[16];
    #pragma unroll
    for (int j = 0; j < 16; ++j) { a0[j] = w0[F2B + j0 + j]; a1[j] = a0[j]; }
    #pragma unroll 2
    for (int i0 = 0; i0 < 16; ++i0) {
      const u16x4 h0 = *(const u16x4*)&hx[rid * 68 + i0 * 4];
      const u16x4 h1v = *(const u16x4*)&hx[(rid + 128) * 68 + i0 * 4];
      #pragma unroll
      for (int u = 0; u < 4; ++u) {
        const float v0 = b2f(h0[u]), v1 = b2f(h1v[u]);
        const f32x4* wr = (const f32x4*)&w0[F2W + (i0 * 4 + u) * 64 + j0];
        #pragma unroll
        for (int c = 0; c < 4; ++c) {
          f32x4 wv = wr[c];
          #pragma unroll
          for (int t = 0; t < 4; ++t) {
            a0[c*4+t] += v0 * wv[t];
            a1[c*4+t] += v1 * wv[t];
          }
        }
      }
    }
    __syncthreads();
    #pragma unroll
    for (int j = 0; j < 16; ++j) {
      hx[rid * 68 + j0 + j]        = f2b(ftanh(a0[j]));
      hx[(rid + 128) * 68 + j0 + j] = f2b(ftanh(a1[j]));
    }
  }
  __syncthreads();
  // fc3: msg = l2norm(h2 @ w3 + b3)
  const int j0m = sub * 8;
  float m0[8], m1[8];
  #pragma unroll
  for (int j = 0; j < 8; ++j) { m0[j] = w0[F3B + j0m + j]; m1[j] = m0[j]; }
  #pragma unroll 2
  for (int i0 = 0; i0 < 16; ++i0) {
    const u16x4 h0 = *(const u16x4*)&hx[rid * 68 + i0 * 4];
    const u16x4 h1v = *(const u16x4*)&hx[(rid + 128) * 68 + i0 * 4];
    #pragma unroll
    for (int u = 0; u < 4; ++u) {
      const float v0 = b2f(h0[u]), v1 = b2f(h1v[u]);
      const f32x4* wr = (const f32x4*)&w0[F3W + (i0 * 4 + u) * 32 + j0m];
      #pragma unroll
      for (int c = 0; c < 2; ++c) {
        f32x4 wv = wr[c];
        #pragma unroll
        for (int t = 0; t < 4; ++t) {
          m0[c*4+t] += v0 * wv[t];
          m1[c*4+t] += v1 * wv[t];
        }
      }
    }
  }
  float sm0 = 0.f, sm1 = 0.f;
  #pragma unroll
  for (int j = 0; j < 8; ++j) { sm0 += m0[j] * m0[j]; sm1 += m1[j] * m1[j]; }
  sm0 += __shfl_xor(sm0, 1, 64); sm0 += __shfl_xor(sm0, 2, 64);
  sm1 += __shfl_xor(sm1, 1, 64); sm1 += __shfl_xor(sm1, 2, 64);
  const float sc0 = 1.f / fmaxf(sqrtf(sm0), 1e-12f);
  const float sc1 = 1.f / fmaxf(sqrtf(sm1), 1e-12f);
  __syncthreads();                    // hx reads done; overwrite as msg
  #pragma unroll
  for (int j = 0; j < 8; ++j) {
    hx[rid * 68 + j0m + j]        = f2b(m0[j] * sc0);
    hx[(rid + 128) * 68 + j0m + j] = f2b(m1[j] * sc1);
  }
  __syncthreads();
  // assemble xum rows (pos/action reloaded from global; sa regs long dead)
  #pragma unroll
  for (int rr = 0; rr < 2; ++rr) {
    const long gr = rr ? g1 : g0;
    const int  lr = rid + rr * 128;
    float pos[3];
    pos[0] = P.state[gr * 32 + 0];
    pos[1] = P.state[gr * 32 + 1];
    pos[2] = P.state[gr * 32 + 2];
    const float act = P.action[gr];
    u16x8 v0, v1;
    #pragma unroll
    for (int t = 0; t < 16; ++t) {
      const int c = j0 + t;
      unsigned short u;
      if      (c < 3)  u = f2b(pos[c]);
      else if (c < 6)  u = f2b(pos[c - 3]);
      else if (c < 38) u = hx[lr * 68 + (c - 6)];
      else if (c == 38) u = f2b(act);
      else if (c == 39) u = 0x3f80;
      else              u = 0;
      if (t < 8) v0[t] = u; else v1[t - 8] = u;
    }
    unsigned short* dst = P.xum + (size_t)gr * 64 + j0;
    *(u16x8*)dst = v0;
    *(u16x8*)(dst + 8) = v1;
  }
}

// ---------------- mlp kernel (R12 verbatim) ----------------
struct P1 {
  const unsigned short* img; const unsigned short* xum;
  const float* q1b2; const float* q1w3; const float* q1b3;
  const float* q2b2; const float* q2w3; const float* q2b3;
  float* out;
};

__global__ __launch_bounds__(ML_THR, 2) void mlp_kernel(P1 P) {
  __shared__ __align__(16) unsigned short h1[ML_ROWS * H1S];
  __shared__ float xred[ML_ROWS * 4];

  const int tid  = threadIdx.x;
  const int lane = tid & 63, w = tid >> 6;        // 8 waves
  const int rl = lane & 15, g = lane >> 4;

  const int rp = w & 3, ch = w >> 2;              // layer1 mapping
  const int wm = w >> 2, wn = w & 3;              // layer2 mapping

  const unsigned short* xr0 = P.xum + ((size_t)blockIdx.x * ML_ROWS + rp * 32 + rl) * 64;
  const bf16x8 af0k0 = ld8(xr0 + g * 8);
  const bf16x8 af0k1 = ld8(xr0 + 32 + g * 8);
  const unsigned short* xr1 = xr0 + 16 * 64;
  const bf16x8 af1k0 = ld8(xr1 + g * 8);
  const bf16x8 af1k1 = ld8(xr1 + 32 + g * 8);

  for (int q = 0; q < 2; ++q) {
    // ---- layer1 (swapped operands): 13 nt x 2 row-tiles, depth-2 pipeline --
    {
      const unsigned short* w1f = P.img + ((size_t)(q * 312 + ch * 26)) * 512 + lane * 8;
      unsigned short* h1w0 = &h1[(size_t)(rp * 32 + rl) * H1S + ch * 208 + g * 4];
      unsigned short* h1w1 = &h1[(size_t)(rp * 32 + 16 + rl) * H1S + ch * 208 + g * 4];
      bf16x8 wA0 = ld8(w1f + 0 * 512), wA1 = ld8(w1f + 1 * 512);
      bf16x8 wB0 = ld8(w1f + 2 * 512), wB1 = ld8(w1f + 3 * 512);
      for (int t = 0; t < 13; t += 2) {
        {
          f32x4 a = (f32x4){0.f, 0.f, 0.f, 0.f};
          f32x4 b = (f32x4){0.f, 0.f, 0.f, 0.f};
          a = MFMA(wA0, af0k0, a); a = MFMA(wA1, af0k1, a);
          b = MFMA(wA0, af1k0, b); b = MFMA(wA1, af1k1, b);
          if (t + 2 < 13) {
            wA0 = ld8(w1f + (size_t)((t + 2) * 2) * 512);
            wA1 = ld8(w1f + (size_t)((t + 2) * 2 + 1) * 512);
          }
          unsigned int p01, p23, q01, q23;
          const float a0 = fmaxf(a[0], 0.f), a1 = fmaxf(a[1], 0.f);
          const float a2 = fmaxf(a[2], 0.f), a3 = fmaxf(a[3], 0.f);
          const float b0 = fmaxf(b[0], 0.f), b1 = fmaxf(b[1], 0.f);
          const float b2 = fmaxf(b[2], 0.f), b3 = fmaxf(b[3], 0.f);
          asm("v_cvt_pk_bf16_f32 %0, %1, %2" : "=v"(p01) : "v"(a0), "v"(a1));
          asm("v_cvt_pk_bf16_f32 %0, %1, %2" : "=v"(p23) : "v"(a2), "v"(a3));
          asm("v_cvt_pk_bf16_f32 %0, %1, %2" : "=v"(q01) : "v"(b0), "v"(b1));
          asm("v_cvt_pk_bf16_f32 %0, %1, %2" : "=v"(q23) : "v"(b2), "v"(b3));
          u32x2 pk; pk[0] = p01; pk[1] = p23;
          u32x2 qk; qk[0] = q01; qk[1] = q23;
          *(u32x2*)(h1w0 + t * 16) = pk;
          *(u32x2*)(h1w1 + t * 16) = qk;
        }
        if (t + 1 < 13) {
          f32x4 a = (f32x4){0.f, 0.f, 0.f, 0.f};
          f32x4 b = (f32x4){0.f, 0.f, 0.f, 0.f};
          a = MFMA(wB0, af0k0, a); a = MFMA(wB1, af0k1, a);
          b = MFMA(wB0, af1k0, b); b = MFMA(wB1, af1k1, b);
          if (t + 3 < 13) {
            wB0 = ld8(w1f + (size_t)((t + 3) * 2) * 512);
            wB1 = ld8(w1f + (size_t)((t + 3) * 2 + 1) * 512);
          }
          unsigned int p01, p23, q01, q23;
          const float a0 = fmaxf(a[0], 0.f), a1 = fmaxf(a[1], 0.f);
          const float a2 = fmaxf(a[2], 0.f), a3 = fmaxf(a[3], 0.f);
          const float b0 = fmaxf(b[0], 0.f), b1 = fmaxf(b[1], 0.f);
          const float b2 = fmaxf(b[2], 0.f), b3 = fmaxf(b[3], 0.f);
          asm("v_cvt_pk_bf16_f32 %0, %1, %2" : "=v"(p01) : "v"(a0), "v"(a1));
          asm("v_cvt_pk_bf16_f32 %0, %1, %2" : "=v"(p23) : "v"(a2), "v"(a3));
          asm("v_cvt_pk_bf16_f32 %0, %1, %2" : "=v"(q01) : "v"(b0), "v"(b1));
          asm("v_cvt_pk_bf16_f32 %0, %1, %2" : "=v"(q23) : "v"(b2), "v"(b3));
          u32x2 pk; pk[0] = p01; pk[1] = p23;
          u32x2 qk; qk[0] = q01; qk[1] = q23;
          *(u32x2*)(h1w0 + (t + 1) * 16) = pk;
          *(u32x2*)(h1w1 + (t + 1) * 16) = qk;
        }
      }
    }
    __syncthreads();

    // ---- layer2: 4 mt x 5 jn x 13 ks; depth-2 pipelined B-frags ----
    f32x4 acc2[4][5];
    #pragma unroll
    for (int mt = 0; mt < 4; ++mt)
      #pragma unroll
      for (int jn = 0; jn < 5; ++jn) acc2[mt][jn] = (f32x4){0.f, 0.f, 0.f, 0.f};
    {
      const unsigned short* w2f = P.img + ((size_t)(q * 312 + 52 + wn * 65)) * 512 + lane * 8;
      bf16x8 bA[5], bB[5];
      #pragma unroll
      for (int jn = 0; jn < 5; ++jn) bA[jn] = ld8(w2f + (size_t)(jn * 13 + 0) * 512);
      #pragma unroll
      for (int jn = 0; jn < 5; ++jn) bB[jn] = ld8(w2f + (size_t)(jn * 13 + 1) * 512);
      for (int ks = 0; ks < 13; ks += 2) {
        {
          bf16x8 am[4];
          #pragma unroll
          for (int mt = 0; mt < 4; ++mt)
            am[mt] = ld8(&h1[(size_t)(wm * 64 + mt * 16 + rl) * H1S + ks * 32 + g * 8]);
          #pragma unroll
          for (int jn = 0; jn < 5; ++jn)
            #pragma unroll
            for (int mt = 0; mt < 4; ++mt)
              acc2[mt][jn] = MFMA(am[mt], bA[jn], acc2[mt][jn]);
          if (ks + 2 < 13) {
            #pragma unroll
            for (int jn = 0; jn < 5; ++jn)
              bA[jn] = ld8(w2f + (size_t)(jn * 13 + ks + 2) * 512);
          }
        }
        if (ks + 1 < 13) {
          bf16x8 am[4];
          #pragma unroll
          for (int mt = 0; mt < 4; ++mt)
            am[mt] = ld8(&h1[(size_t)(wm * 64 + mt * 16 + rl) * H1S + (ks + 1) * 32 + g * 8]);
          #pragma unroll
          for (int jn = 0; jn < 5; ++jn)
            #pragma unroll
            for (int mt = 0; mt < 4; ++mt)
              acc2[mt][jn] = MFMA(am[mt], bB[jn], acc2[mt][jn]);
          if (ks + 3 < 13) {
            #pragma unroll
            for (int jn = 0; jn < 5; ++jn)
              bB[jn] = ld8(w2f + (size_t)(jn * 13 + ks + 3) * 512);
          }
        }
      }
    }

    // ---- epilogue ----
    const float* b2p = q ? P.q2b2 : P.q1b2;
    const float* w3  = q ? P.q2w3 : P.q1w3;
    const float* b3  = q ? P.q2b3 : P.q1b3;
    float xp[4][4];
    #pragma unroll
    for (int mt = 0; mt < 4; ++mt)
      #pragma unroll
      for (int i = 0; i < 4; ++i) xp[mt][i] = 0.f;
    #pragma unroll
    for (int jn = 0; jn < 5; ++jn) {
      const int n = wn * 80 + jn * 16 + rl;
      if (n < 300) {
        const float bv = b2p[n], wv = w3[n];
        #pragma unroll
        for (int mt = 0; mt < 4; ++mt)
          #pragma unroll
          for (int i = 0; i < 4; ++i)
            xp[mt][i] += fmaxf(acc2[mt][jn][i] + bv, 0.f) * wv;
      }
    }
    #pragma unroll
    for (int off = 1; off < 16; off <<= 1)
      #pragma unroll
      for (int mt = 0; mt < 4; ++mt)
        #pragma unroll
        for (int i = 0; i < 4; ++i)
          xp[mt][i] += __shfl_xor(xp[mt][i], off, 64);
    if (rl == 0) {
      #pragma unroll
      for (int mt = 0; mt < 4; ++mt)
        #pragma unroll
        for (int i = 0; i < 4; ++i)
          xred[(wm * 64 + mt * 16 + g * 4 + i) * 4 + wn] = xp[mt][i];
    }
    __syncthreads();
    if (tid < ML_ROWS) {
      const float4 xv = *(const float4*)&xred[tid * 4];
      P.out[(size_t)q * BTOT + (size_t)blockIdx.x * ML_ROWS + tid] =
          xv.x + xv.y + xv.z + xv.w + b3[0];
    }
    __syncthreads();
  }
}

extern "C" void kernel_launch(void* const* d_in, const int* in_sizes, int n_in,
                              void* d_out, int out_size, void* d_ws, size_t ws_size,
                              hipStream_t stream) {
  (void)in_sizes; (void)n_in; (void)out_size; (void)ws_size;
  P0 A;
  A.state  = (const float*)d_in[0];
  A.action = (const float*)d_in[1];
  A.f1w = (const float*)d_in[2]; A.f1b = (const float*)d_in[3];
  A.f2w = (const float*)d_in[4]; A.f2b = (const float*)d_in[5];
  A.f3w = (const float*)d_in[6]; A.f3b = (const float*)d_in[7];
  A.q1w1 = (const float*)d_in[10]; A.q1b1 = (const float*)d_in[11]; A.q1w2 = (const float*)d_in[12];
  A.q2w1 = (const float*)d_in[16]; A.q2b1 = (const float*)d_in[17]; A.q2w2 = (const float*)d_in[18];
  A.ws  = (unsigned short*)d_ws;
  A.xum = (unsigned short*)((unsigned char*)d_ws + XUM_OFF);
  phase0_kernel<<<dim3(PK_BLK + PH_BLK), dim3(PH_THR), 0, stream>>>(A);

  P1 B;
  B.img  = (const unsigned short*)d_ws;
  B.xum  = (const unsigned short*)((unsigned char*)d_ws + XUM_OFF);
  B.q1b2 = (const float*)d_in[13]; B.q1w3 = (const float*)d_in[14]; B.q1b3 = (const float*)d_in[15];
  B.q2b2 = (const float*)d_in[19]; B.q2w3 = (const float*)d_in[20]; B.q2b3 = (const float*)d_in[21];
  B.out  = (float*)d_out;
  mlp_kernel<<<dim3(ML_BLK), dim3(ML_THR), 0, stream>>>(B);
}